// Round 6
// baseline (439.185 us; speedup 1.0000x reference)
//
#include <hip/hip_runtime.h>

// ParallelSelfAttention: S=2048 B=1 H=2048 NH=16 HD=128. I/O f32, internal bf16 MFMA.
// R10 == R9 resubmit (round-5 bench died to container infra; R9 is R8-passed + one
// attribute). R8's async-STAGE split was correct (hbm_gbps 728->975) but the compiler
// picked an 88-VGPR occupancy budget and SPILLED the kst/vst staging registers
// (WRITE_SIZE 8->101MB scratch traffic). We only ever have 2 blocks/CU = 2 waves/SIMD,
// so __launch_bounds__(256,2) raises the VGPR cap to 256: no spill, same occupancy.

#define S_LEN 2048
#define NHEAD 16
#define HDIM  128
#define HID   2048
#define H3    6144

typedef short bf16x8 __attribute__((ext_vector_type(8)));
typedef float f32x4  __attribute__((ext_vector_type(4)));

__device__ __forceinline__ float bf2f(ushort u) {
  union { float f; unsigned int i; } v; v.i = ((unsigned int)u) << 16; return v.f;
}
__device__ __forceinline__ ushort f2bf(float f) {
  union { float f; unsigned int i; } v; v.f = f;
  unsigned int r = v.i + 0x7fffu + ((v.i >> 16) & 1u);
  return (ushort)(r >> 16);
}
__device__ __forceinline__ int4 cvt8(const float* p) {
  float4 a = *(const float4*)p, b = *(const float4*)(p + 4);
  union { ushort u[8]; int4 v; } r;
  r.u[0] = f2bf(a.x); r.u[1] = f2bf(a.y); r.u[2] = f2bf(a.z); r.u[3] = f2bf(a.w);
  r.u[4] = f2bf(b.x); r.u[5] = f2bf(b.y); r.u[6] = f2bf(b.z); r.u[7] = f2bf(b.w);
  return r.v;
}

// async global->LDS DMA, 16B per lane; LDS dest = wave-uniform base + lane*16
typedef __attribute__((address_space(1))) const unsigned int gu32;
typedef __attribute__((address_space(3))) unsigned int lu32;
__device__ __forceinline__ void async16(const void* g, void* l) {
  __builtin_amdgcn_global_load_lds((gu32*)g, (lu32*)l, 16, 0, 0);
}

// ---- f32 -> bf16 elementwise convert (8 elems/thread) -----------------------------------
__global__ __launch_bounds__(256) void cvt_bf16(const float* __restrict__ src,
                                                ushort* __restrict__ dst, int n8) {
  int i = blockIdx.x * 256 + threadIdx.x;
  if (i < n8) *(int4*)&dst[(size_t)i * 8] = cvt8(&src[(size_t)i * 8]);
}

// ---- Fast GEMM: C[M,N] = A @ W^T (+bias). A,W bf16; staging via global_load_lds. --------
template<int BM, int BN, bool HAS_BIAS, bool OUT_F32>
__global__ __launch_bounds__(256) void gemm_async(const ushort* __restrict__ A,
                                                  const ushort* __restrict__ W,
                                                  const float* __restrict__ bias,
                                                  void* __restrict__ Cv,
                                                  int N, int K, int AS, int AH) {
  __shared__ __align__(16) ushort As[BM * 32];
  __shared__ __align__(16) ushort Ws[BN * 32];
  const int tid  = threadIdx.x;
  const int lane = tid & 63;
  const int w    = tid >> 6;
  const int wr   = w >> 1, wc = w & 1;
  const int quad = lane >> 4, ln15 = lane & 15;
  const int tm = blockIdx.y * BM, tn = blockIdx.x * BN;
  constexpr int MI = BM / 32, NJ = BN / 32;

  f32x4 acc[MI][NJ];
#pragma unroll
  for (int i = 0; i < MI; ++i)
#pragma unroll
    for (int j = 0; j < NJ; ++j) acc[i][j] = (f32x4){0.f, 0.f, 0.f, 0.f};

  const int lrow = lane >> 2;          // 0..15 within a 16-row issue
  const int lcol = (lane & 3) * 8;     // k element offset within 32-chunk

  for (int k0 = 0; k0 < K; k0 += 32) {
    const int aoff = (k0 >> 7) * AH + (k0 & 127) + lcol;
    for (int r = w; r < (BM + BN) / 16; r += 4) {
      if (r < BM / 16) {
        async16(&A[(size_t)(tm + r * 16 + lrow) * AS + aoff], &As[r * 16 * 32]);
      } else {
        const int rb = r - BM / 16;
        async16(&W[(size_t)(tn + rb * 16 + lrow) * K + k0 + lcol], &Ws[rb * 16 * 32]);
      }
    }
    __syncthreads();
    bf16x8 af[MI], bw[NJ];
#pragma unroll
    for (int i = 0; i < MI; ++i)
      af[i] = *(const bf16x8*)&As[((BM / 2) * wr + 16 * i + ln15) * 32 + quad * 8];
#pragma unroll
    for (int j = 0; j < NJ; ++j)
      bw[j] = *(const bf16x8*)&Ws[((BN / 2) * wc + 16 * j + ln15) * 32 + quad * 8];
#pragma unroll
    for (int i = 0; i < MI; ++i)
#pragma unroll
      for (int j = 0; j < NJ; ++j)
        acc[i][j] = __builtin_amdgcn_mfma_f32_16x16x32_bf16(af[i], bw[j], acc[i][j], 0, 0, 0);
    __syncthreads();
  }

#pragma unroll
  for (int i = 0; i < MI; ++i)
#pragma unroll
    for (int j = 0; j < NJ; ++j) {
      int col = tn + (BN / 2) * wc + 16 * j + ln15;
      float badd = HAS_BIAS ? bias[col] : 0.0f;
#pragma unroll
      for (int r = 0; r < 4; ++r) {
        int row = tm + (BM / 2) * wr + 16 * i + 4 * quad + r;
        float val = acc[i][j][r] + badd;
        if (OUT_F32) ((float*)Cv)[(size_t)row * N + col] = val;
        else         ((ushort*)Cv)[(size_t)row * N + col] = f2bf(val);
      }
    }
}

// ---- Fallback GEMM (round-4 proven): A f32-or-bf16, W f32, cvt in staging ---------------
template<bool A_F32, bool HAS_BIAS, bool OUT_F32>
__global__ __launch_bounds__(256) void gemm_bt(const void* __restrict__ Av,
                                               const float* __restrict__ W,
                                               const float* __restrict__ bias,
                                               void* __restrict__ Cv,
                                               int M, int N, int K, int AS, int AH) {
  __shared__ __align__(16) ushort As[128 * 40];
  __shared__ __align__(16) ushort Ws[128 * 40];
  const int tid  = threadIdx.x;
  const int lane = tid & 63;
  const int w    = tid >> 6;
  const int wr   = w >> 1, wc = w & 1;
  const int quad = lane >> 4, ln15 = lane & 15;
  const int tm = blockIdx.y * 128, tn = blockIdx.x * 128;

  f32x4 acc[4][4];
#pragma unroll
  for (int i = 0; i < 4; ++i)
#pragma unroll
    for (int j = 0; j < 4; ++j) acc[i][j] = (f32x4){0.f, 0.f, 0.f, 0.f};

  const int row0 = tid >> 2, row1 = row0 + 64;
  const int kp   = (tid & 3) * 8;

  for (int k0 = 0; k0 < K; k0 += 32) {
    const int ka   = k0 + kp;
    const int aoff = (ka >> 7) * AH + (ka & 127);
    if (A_F32) {
      const float* A = (const float*)Av;
      *(int4*)&As[row0 * 40 + kp] = cvt8(&A[(size_t)(tm + row0) * AS + aoff]);
      *(int4*)&As[row1 * 40 + kp] = cvt8(&A[(size_t)(tm + row1) * AS + aoff]);
    } else {
      const ushort* A = (const ushort*)Av;
      *(int4*)&As[row0 * 40 + kp] = *(const int4*)&A[(size_t)(tm + row0) * AS + aoff];
      *(int4*)&As[row1 * 40 + kp] = *(const int4*)&A[(size_t)(tm + row1) * AS + aoff];
    }
    *(int4*)&Ws[row0 * 40 + kp] = cvt8(&W[(size_t)(tn + row0) * K + ka]);
    *(int4*)&Ws[row1 * 40 + kp] = cvt8(&W[(size_t)(tn + row1) * K + ka]);
    __syncthreads();
    bf16x8 af[4], bw[4];
#pragma unroll
    for (int i = 0; i < 4; ++i)
      af[i] = *(const bf16x8*)&As[(64 * wr + 16 * i + ln15) * 40 + quad * 8];
#pragma unroll
    for (int j = 0; j < 4; ++j)
      bw[j] = *(const bf16x8*)&Ws[(64 * wc + 16 * j + ln15) * 40 + quad * 8];
#pragma unroll
    for (int i = 0; i < 4; ++i)
#pragma unroll
      for (int j = 0; j < 4; ++j)
        acc[i][j] = __builtin_amdgcn_mfma_f32_16x16x32_bf16(af[i], bw[j], acc[i][j], 0, 0, 0);
    __syncthreads();
  }

#pragma unroll
  for (int i = 0; i < 4; ++i)
#pragma unroll
    for (int j = 0; j < 4; ++j) {
      int col = tn + 64 * wc + 16 * j + ln15;
      float badd = HAS_BIAS ? bias[col] : 0.0f;
#pragma unroll
      for (int r = 0; r < 4; ++r) {
        int row = tm + 64 * wr + 16 * i + 4 * quad + r;
        float val = acc[i][j][r] + badd;
        if (OUT_F32) ((float*)Cv)[(size_t)row * N + col] = val;
        else         ((ushort*)Cv)[(size_t)row * N + col] = f2bf(val);
      }
    }
}

// ---- RoPE in place on q,k of mixed[s][n*384 + {q,k,v}] (bf16), float sincos -------------
__global__ __launch_bounds__(256) void rope_kernel(ushort* __restrict__ mixed) {
  int t = blockIdx.x * 256 + threadIdx.x;   // S*NH*64 threads
  int d = t & 63;
  int n = (t >> 6) & (NHEAD - 1);
  int s = t >> 10;
  ushort* base = mixed + (size_t)s * H3 + n * 384;
  float invf = exp2f((float)d * (-13.287712379549449f / 64.0f));
  float ang = (float)s * invf;
  float si, c; sincosf(ang, &si, &c);
  float q0 = bf2f(base[d]),       q1 = bf2f(base[64 + d]);
  float k0 = bf2f(base[128 + d]), k1 = bf2f(base[192 + d]);
  base[d]       = f2bf(q0 * c - q1 * si);
  base[64 + d]  = f2bf(q1 * c + q0 * si);
  base[128 + d] = f2bf(k0 * c - k1 * si);
  base[192 + d] = f2bf(k1 * c + k0 * si);
}

// ---- V transpose: mixed v-part (bf16) -> vt[n][d][s] ------------------------------------
__global__ __launch_bounds__(256) void v_transpose(const ushort* __restrict__ mixed,
                                                   ushort* __restrict__ vt) {
  __shared__ __align__(16) ushort Vl[64 * 136];
  const int tid = threadIdx.x;
  const int sb = blockIdx.x;
  const int n  = blockIdx.y;
#pragma unroll
  for (int it = 0; it < 4; ++it) {
    int c = tid + it * 256;
    int row = c >> 4, dp = (c & 15) * 8;
    *(int4*)&Vl[row * 136 + dp] =
        *(const int4*)&mixed[(size_t)(sb * 64 + row) * H3 + n * 384 + 256 + dp];
  }
  __syncthreads();
#pragma unroll
  for (int it = 0; it < 4; ++it) {
    int c = tid + it * 256;
    int d = c >> 3, sp = (c & 7) * 8;
    union { ushort u[8]; int4 v; } pk;
#pragma unroll
    for (int e = 0; e < 8; ++e) pk.u[e] = Vl[(sp + e) * 136 + d];
    *(int4*)&vt[((size_t)(n * 128 + d)) * S_LEN + sb * 64 + sp] = pk.v;
  }
}

// ---- Flash attention R10: round-0 compute + async-split staging, no-spill VGPR budget ---
__global__ __launch_bounds__(256, 2) void attn_kernel(const ushort* __restrict__ mixed,
                                                      const ushort* __restrict__ vt,
                                                      ushort* __restrict__ ctx,
                                                      int CS, int CH) {
  __shared__ __align__(16) ushort Ks[64 * 136];
  __shared__ __align__(16) ushort Vt[128 * 72];
  __shared__ __align__(16) float  Ss[4 * 16 * 68];

  const int tid  = threadIdx.x;
  const int lane = tid & 63;
  const int w    = tid >> 6;
  const int quad = lane >> 4, ln15 = lane & 15;
  const int qb = blockIdx.x;
  const int n  = blockIdx.y;
  const float scale = 0.08838834764831845f;

  bf16x8 aqr[4];
#pragma unroll
  for (int ks = 0; ks < 4; ++ks)
    aqr[ks] = *(const bf16x8*)&mixed[(size_t)(qb * 64 + 16 * w + ln15) * H3 + n * 384
                                     + ks * 32 + quad * 8];

  f32x4 acc_o[8];
#pragma unroll
  for (int jt = 0; jt < 8; ++jt) acc_o[jt] = (f32x4){0.f, 0.f, 0.f, 0.f};
  float m_run[4], l_run[4];
#pragma unroll
  for (int r = 0; r < 4; ++r) { m_run[r] = -1e30f; l_run[r] = 0.0f; }

  float* Ssw = &Ss[w * 16 * 68];

  // Staging registers: tile kt+1 K and V rows (per-thread 4+4 int4 = 32 VGPRs).
  // __launch_bounds__(256,2) gives the allocator a 256-VGPR budget so these stay in
  // registers (R8: 88-VGPR budget spilled them -> 101MB scratch writes).
  int4 kst[4], vst[4];

#define ATTN_LOADREGS(KT)                                                               \
  {                                                                                     \
    _Pragma("unroll")                                                                   \
    for (int it = 0; it < 4; ++it) {                                                    \
      int c = tid + it * 256;                                                           \
      int krow = c >> 4, kdp = (c & 15) * 8;                                            \
      int vd = c >> 3, vsp = (c & 7) * 8;                                               \
      kst[it] = *(const int4*)&mixed[(size_t)((KT) * 64 + krow) * H3 + n * 384 + 128 + kdp]; \
      vst[it] = *(const int4*)&vt[((size_t)(n * 128 + vd)) * S_LEN + (KT) * 64 + vsp];  \
    }                                                                                   \
  }

#define ATTN_WRITELDS()                                                                 \
  {                                                                                     \
    _Pragma("unroll")                                                                   \
    for (int it = 0; it < 4; ++it) {                                                    \
      int c = tid + it * 256;                                                           \
      int krow = c >> 4, kdp = (c & 15) * 8;                                            \
      int vd = c >> 3, vsp = (c & 7) * 8;                                               \
      *(int4*)&Ks[krow * 136 + kdp] = kst[it];                                          \
      *(int4*)&Vt[vd * 72 + vsp]    = vst[it];                                          \
    }                                                                                   \
  }

  // Prologue: stage tile 0
  ATTN_LOADREGS(0);
  ATTN_WRITELDS();
  __syncthreads();

  for (int kt = 0; kt <= qb; ++kt) {
    // Issue next tile's global loads early (latency hidden under compute below)
    if (kt < qb) ATTN_LOADREGS(kt + 1);

    // ---- compute on current LDS tile (identical to round-0) ----
    f32x4 sacc[4];
#pragma unroll
    for (int jt = 0; jt < 4; ++jt) sacc[jt] = (f32x4){0.f, 0.f, 0.f, 0.f};
#pragma unroll
    for (int ks = 0; ks < 4; ++ks) {
#pragma unroll
      for (int jt = 0; jt < 4; ++jt) {
        bf16x8 bk = *(const bf16x8*)&Ks[(16 * jt + ln15) * 136 + ks * 32 + quad * 8];
        sacc[jt] = __builtin_amdgcn_mfma_f32_16x16x32_bf16(aqr[ks], bk, sacc[jt], 0, 0, 0);
      }
    }

    float sv[4][4];
    const int ig = qb * 64 + 16 * w + 4 * quad;
#pragma unroll
    for (int jt = 0; jt < 4; ++jt) {
      int jg = kt * 64 + 16 * jt + ln15;
#pragma unroll
      for (int r = 0; r < 4; ++r) {
        float x = sacc[jt][r] * scale;
        sv[jt][r] = (jg > ig + r) ? -10000.0f : x;
      }
    }

    float tmx[4];
#pragma unroll
    for (int r = 0; r < 4; ++r)
      tmx[r] = fmaxf(fmaxf(sv[0][r], sv[1][r]), fmaxf(sv[2][r], sv[3][r]));
#pragma unroll
    for (int m = 1; m <= 8; m <<= 1)
#pragma unroll
      for (int r = 0; r < 4; ++r) tmx[r] = fmaxf(tmx[r], __shfl_xor(tmx[r], m));

    float alpha[4];
#pragma unroll
    for (int r = 0; r < 4; ++r) {
      float m_new = fmaxf(m_run[r], tmx[r]);
      alpha[r] = __expf(m_run[r] - m_new);
      m_run[r] = m_new;
    }

    float ps[4] = {0.f, 0.f, 0.f, 0.f};
#pragma unroll
    for (int jt = 0; jt < 4; ++jt)
#pragma unroll
      for (int r = 0; r < 4; ++r) {
        float p = __expf(sv[jt][r] - m_run[r]);
        Ssw[(4 * quad + r) * 68 + 16 * jt + ln15] = p;
        ps[r] += p;
      }
#pragma unroll
    for (int m = 1; m <= 8; m <<= 1)
#pragma unroll
      for (int r = 0; r < 4; ++r) ps[r] += __shfl_xor(ps[r], m);
#pragma unroll
    for (int r = 0; r < 4; ++r) l_run[r] = alpha[r] * l_run[r] + ps[r];

#pragma unroll
    for (int jt = 0; jt < 8; ++jt)
#pragma unroll
      for (int r = 0; r < 4; ++r) acc_o[jt][r] *= alpha[r];
#pragma unroll
    for (int ks = 0; ks < 2; ++ks) {
      const float* pp = &Ssw[ln15 * 68 + ks * 32 + quad * 8];
      float4 p0 = *(const float4*)(pp);
      float4 p1 = *(const float4*)(pp + 4);
      bf16x8 ap;
      ap[0] = (short)f2bf(p0.x); ap[1] = (short)f2bf(p0.y);
      ap[2] = (short)f2bf(p0.z); ap[3] = (short)f2bf(p0.w);
      ap[4] = (short)f2bf(p1.x); ap[5] = (short)f2bf(p1.y);
      ap[6] = (short)f2bf(p1.z); ap[7] = (short)f2bf(p1.w);
#pragma unroll
      for (int jt = 0; jt < 8; ++jt) {
        bf16x8 bv = *(const bf16x8*)&Vt[(16 * jt + ln15) * 72 + ks * 32 + quad * 8];
        acc_o[jt] = __builtin_amdgcn_mfma_f32_16x16x32_bf16(ap, bv, acc_o[jt], 0, 0, 0);
      }
    }
    // ---- end compute ----

    if (kt < qb) {
      __syncthreads();        // all waves done reading Ks/Vt (vmcnt drain = prefetch done)
      ATTN_WRITELDS();        // write tile kt+1
      __syncthreads();        // tile ready for next iteration
    }
  }
#undef ATTN_LOADREGS
#undef ATTN_WRITELDS

  float rinv[4];
#pragma unroll
  for (int r = 0; r < 4; ++r) rinv[r] = 1.0f / l_run[r];
#pragma unroll
  for (int jt = 0; jt < 8; ++jt)
#pragma unroll
    for (int r = 0; r < 4; ++r) {
      int row = qb * 64 + 16 * w + 4 * quad + r;
      int col = 16 * jt + ln15;
      ctx[(size_t)row * CS + n * CH + col] = f2bf(acc_o[jt][r] * rinv[r]);
    }
}

// ---- launch ------------------------------------------------------------------------------
extern "C" void kernel_launch(void* const* d_in, const int* in_sizes, int n_in,
                              void* d_out, int out_size, void* d_ws, size_t ws_size,
                              hipStream_t stream) {
  const float* hidden  = (const float*)d_in[0];
  const float* w_qkv   = (const float*)d_in[2];
  const float* b_qkv   = (const float*)d_in[3];
  const float* w_dense = (const float*)d_in[4];
  float* out = (float*)d_out;

  char* ws = (char*)d_ws;

  const size_t wq_b    = (size_t)H3 * HID * 2;             // 25,165,824
  const size_t h_b     = (size_t)S_LEN * HID * 2;          //  8,388,608
  const size_t mixed_b = (size_t)S_LEN * H3 * 2;           // 25,165,824
  const size_t vt_b    = (size_t)NHEAD * HDIM * S_LEN * 2; //  8,388,608
  const size_t fast_need = wq_b + h_b + mixed_b + vt_b;    // 67,108,864 (64 MiB)

  if (ws_size >= fast_need) {
    // fast path: bf16 pre-convert + async-staged GEMMs
    ushort* WQ    = (ushort*)ws;                       // w_qkv bf16 (WD reuses this later)
    ushort* Hbf   = (ushort*)(ws + wq_b);
    ushort* mixed = (ushort*)(ws + wq_b + h_b);
    ushort* vt    = (ushort*)(ws + wq_b + h_b + mixed_b);
    ushort* WD    = WQ;                                // w_qkv dead after QKV GEMM
    ushort* ctx   = mixed;                             // q-slots of mixed (race-free)

    cvt_bf16<<<2048, 256, 0, stream>>>(hidden, Hbf, S_LEN * HID / 8);
    cvt_bf16<<<6144, 256, 0, stream>>>(w_qkv, WQ, H3 * HID / 8);
    gemm_async<128, 128, true, false><<<dim3(48, 16), 256, 0, stream>>>(
        Hbf, WQ, b_qkv, mixed, H3, HID, HID, 128);
    rope_kernel<<<8192, 256, 0, stream>>>(mixed);
    v_transpose<<<dim3(32, 16), 256, 0, stream>>>(mixed, vt);
    attn_kernel<<<dim3(32, 16), 256, 0, stream>>>(mixed, vt, ctx, H3, 384);
    cvt_bf16<<<2048, 256, 0, stream>>>(w_dense, WD, HID * HID / 8);
    gemm_async<64, 128, false, true><<<dim3(16, 32), 256, 0, stream>>>(
        ctx, WD, nullptr, out, HID, HID, H3, 384);
  } else {
    // fallback: round-4 proven path
    ushort* mixed = (ushort*)ws;
    ushort* vt    = (ushort*)(ws + mixed_b);
    const bool big = ws_size >= mixed_b + vt_b + (size_t)S_LEN * HID * 2;
    ushort* ctx = big ? (ushort*)(ws + mixed_b + vt_b) : mixed;
    const int CS = big ? HID  : H3;
    const int CH = big ? HDIM : 384;

    gemm_bt<true, true, false><<<dim3(48, 16), 256, 0, stream>>>(
        hidden, w_qkv, b_qkv, mixed, S_LEN, H3, HID, HID, HDIM);
    rope_kernel<<<8192, 256, 0, stream>>>(mixed);
    v_transpose<<<dim3(32, 16), 256, 0, stream>>>(mixed, vt);
    attn_kernel<<<dim3(32, 16), 256, 0, stream>>>(mixed, vt, ctx, CS, CH);
    gemm_bt<false, false, true><<<dim3(16, 16), 256, 0, stream>>>(
        ctx, w_dense, nullptr, out, S_LEN, HID, HID, CS, CH);
  }
}

// Round 7
// 345.132 us; speedup vs baseline: 1.2725x; 1.2725x over previous
//
#include <hip/hip_runtime.h>

// ParallelSelfAttention: S=2048 B=1 H=2048 NH=16 HD=128. I/O f32, internal bf16 MFMA.
// R11: attn staging via global_load_lds DMA (zero staging registers -> no scratch, which
// killed R8-R10: compiler refused to keep reg-staged tiles live across MFMA, 100MB scratch).
// K double-buffered [2][64][128] linear (DMA dest), V single [128][64] staged during
// QK+softmax of the same iter, P stored bf16 [16][72]/wave. Bank conflicts fixed via
// rule-21 both-sides XOR: linear LDS dest + inverse-swizzled GLOBAL source + swizzled read
// (chunk ^= row&7). LDS 58368B < 64KB static limit, 2 blocks/CU preserved.

#define S_LEN 2048
#define NHEAD 16
#define HDIM  128
#define HID   2048
#define H3    6144

typedef short bf16x8 __attribute__((ext_vector_type(8)));
typedef float f32x4  __attribute__((ext_vector_type(4)));

__device__ __forceinline__ float bf2f(ushort u) {
  union { float f; unsigned int i; } v; v.i = ((unsigned int)u) << 16; return v.f;
}
__device__ __forceinline__ ushort f2bf(float f) {
  union { float f; unsigned int i; } v; v.f = f;
  unsigned int r = v.i + 0x7fffu + ((v.i >> 16) & 1u);
  return (ushort)(r >> 16);
}
__device__ __forceinline__ int4 cvt8(const float* p) {
  float4 a = *(const float4*)p, b = *(const float4*)(p + 4);
  union { ushort u[8]; int4 v; } r;
  r.u[0] = f2bf(a.x); r.u[1] = f2bf(a.y); r.u[2] = f2bf(a.z); r.u[3] = f2bf(a.w);
  r.u[4] = f2bf(b.x); r.u[5] = f2bf(b.y); r.u[6] = f2bf(b.z); r.u[7] = f2bf(b.w);
  return r.v;
}

// async global->LDS DMA, 16B per lane; LDS dest = wave-uniform base + lane*16
typedef __attribute__((address_space(1))) const unsigned int gu32;
typedef __attribute__((address_space(3))) unsigned int lu32;
__device__ __forceinline__ void async16(const void* g, void* l) {
  __builtin_amdgcn_global_load_lds((gu32*)g, (lu32*)l, 16, 0, 0);
}

// ---- f32 -> bf16 elementwise convert (8 elems/thread) -----------------------------------
__global__ __launch_bounds__(256) void cvt_bf16(const float* __restrict__ src,
                                                ushort* __restrict__ dst, int n8) {
  int i = blockIdx.x * 256 + threadIdx.x;
  if (i < n8) *(int4*)&dst[(size_t)i * 8] = cvt8(&src[(size_t)i * 8]);
}

// ---- Fast GEMM: C[M,N] = A @ W^T (+bias). A,W bf16; staging via global_load_lds. --------
template<int BM, int BN, bool HAS_BIAS, bool OUT_F32>
__global__ __launch_bounds__(256) void gemm_async(const ushort* __restrict__ A,
                                                  const ushort* __restrict__ W,
                                                  const float* __restrict__ bias,
                                                  void* __restrict__ Cv,
                                                  int N, int K, int AS, int AH) {
  __shared__ __align__(16) ushort As[BM * 32];
  __shared__ __align__(16) ushort Ws[BN * 32];
  const int tid  = threadIdx.x;
  const int lane = tid & 63;
  const int w    = tid >> 6;
  const int wr   = w >> 1, wc = w & 1;
  const int quad = lane >> 4, ln15 = lane & 15;
  const int tm = blockIdx.y * BM, tn = blockIdx.x * BN;
  constexpr int MI = BM / 32, NJ = BN / 32;

  f32x4 acc[MI][NJ];
#pragma unroll
  for (int i = 0; i < MI; ++i)
#pragma unroll
    for (int j = 0; j < NJ; ++j) acc[i][j] = (f32x4){0.f, 0.f, 0.f, 0.f};

  const int lrow = lane >> 2;          // 0..15 within a 16-row issue
  const int lcol = (lane & 3) * 8;     // k element offset within 32-chunk

  for (int k0 = 0; k0 < K; k0 += 32) {
    const int aoff = (k0 >> 7) * AH + (k0 & 127) + lcol;
    for (int r = w; r < (BM + BN) / 16; r += 4) {
      if (r < BM / 16) {
        async16(&A[(size_t)(tm + r * 16 + lrow) * AS + aoff], &As[r * 16 * 32]);
      } else {
        const int rb = r - BM / 16;
        async16(&W[(size_t)(tn + rb * 16 + lrow) * K + k0 + lcol], &Ws[rb * 16 * 32]);
      }
    }
    __syncthreads();
    bf16x8 af[MI], bw[NJ];
#pragma unroll
    for (int i = 0; i < MI; ++i)
      af[i] = *(const bf16x8*)&As[((BM / 2) * wr + 16 * i + ln15) * 32 + quad * 8];
#pragma unroll
    for (int j = 0; j < NJ; ++j)
      bw[j] = *(const bf16x8*)&Ws[((BN / 2) * wc + 16 * j + ln15) * 32 + quad * 8];
#pragma unroll
    for (int i = 0; i < MI; ++i)
#pragma unroll
      for (int j = 0; j < NJ; ++j)
        acc[i][j] = __builtin_amdgcn_mfma_f32_16x16x32_bf16(af[i], bw[j], acc[i][j], 0, 0, 0);
    __syncthreads();
  }

#pragma unroll
  for (int i = 0; i < MI; ++i)
#pragma unroll
    for (int j = 0; j < NJ; ++j) {
      int col = tn + (BN / 2) * wc + 16 * j + ln15;
      float badd = HAS_BIAS ? bias[col] : 0.0f;
#pragma unroll
      for (int r = 0; r < 4; ++r) {
        int row = tm + (BM / 2) * wr + 16 * i + 4 * quad + r;
        float val = acc[i][j][r] + badd;
        if (OUT_F32) ((float*)Cv)[(size_t)row * N + col] = val;
        else         ((ushort*)Cv)[(size_t)row * N + col] = f2bf(val);
      }
    }
}

// ---- Fallback GEMM (round-4 proven): A f32-or-bf16, W f32, cvt in staging ---------------
template<bool A_F32, bool HAS_BIAS, bool OUT_F32>
__global__ __launch_bounds__(256) void gemm_bt(const void* __restrict__ Av,
                                               const float* __restrict__ W,
                                               const float* __restrict__ bias,
                                               void* __restrict__ Cv,
                                               int M, int N, int K, int AS, int AH) {
  __shared__ __align__(16) ushort As[128 * 40];
  __shared__ __align__(16) ushort Ws[128 * 40];
  const int tid  = threadIdx.x;
  const int lane = tid & 63;
  const int w    = tid >> 6;
  const int wr   = w >> 1, wc = w & 1;
  const int quad = lane >> 4, ln15 = lane & 15;
  const int tm = blockIdx.y * 128, tn = blockIdx.x * 128;

  f32x4 acc[4][4];
#pragma unroll
  for (int i = 0; i < 4; ++i)
#pragma unroll
    for (int j = 0; j < 4; ++j) acc[i][j] = (f32x4){0.f, 0.f, 0.f, 0.f};

  const int row0 = tid >> 2, row1 = row0 + 64;
  const int kp   = (tid & 3) * 8;

  for (int k0 = 0; k0 < K; k0 += 32) {
    const int ka   = k0 + kp;
    const int aoff = (ka >> 7) * AH + (ka & 127);
    if (A_F32) {
      const float* A = (const float*)Av;
      *(int4*)&As[row0 * 40 + kp] = cvt8(&A[(size_t)(tm + row0) * AS + aoff]);
      *(int4*)&As[row1 * 40 + kp] = cvt8(&A[(size_t)(tm + row1) * AS + aoff]);
    } else {
      const ushort* A = (const ushort*)Av;
      *(int4*)&As[row0 * 40 + kp] = *(const int4*)&A[(size_t)(tm + row0) * AS + aoff];
      *(int4*)&As[row1 * 40 + kp] = *(const int4*)&A[(size_t)(tm + row1) * AS + aoff];
    }
    *(int4*)&Ws[row0 * 40 + kp] = cvt8(&W[(size_t)(tn + row0) * K + ka]);
    *(int4*)&Ws[row1 * 40 + kp] = cvt8(&W[(size_t)(tn + row1) * K + ka]);
    __syncthreads();
    bf16x8 af[4], bw[4];
#pragma unroll
    for (int i = 0; i < 4; ++i)
      af[i] = *(const bf16x8*)&As[(64 * wr + 16 * i + ln15) * 40 + quad * 8];
#pragma unroll
    for (int j = 0; j < 4; ++j)
      bw[j] = *(const bf16x8*)&Ws[(64 * wc + 16 * j + ln15) * 40 + quad * 8];
#pragma unroll
    for (int i = 0; i < 4; ++i)
#pragma unroll
      for (int j = 0; j < 4; ++j)
        acc[i][j] = __builtin_amdgcn_mfma_f32_16x16x32_bf16(af[i], bw[j], acc[i][j], 0, 0, 0);
    __syncthreads();
  }

#pragma unroll
  for (int i = 0; i < 4; ++i)
#pragma unroll
    for (int j = 0; j < 4; ++j) {
      int col = tn + 64 * wc + 16 * j + ln15;
      float badd = HAS_BIAS ? bias[col] : 0.0f;
#pragma unroll
      for (int r = 0; r < 4; ++r) {
        int row = tm + 64 * wr + 16 * i + 4 * quad + r;
        float val = acc[i][j][r] + badd;
        if (OUT_F32) ((float*)Cv)[(size_t)row * N + col] = val;
        else         ((ushort*)Cv)[(size_t)row * N + col] = f2bf(val);
      }
    }
}

// ---- RoPE in place on q,k of mixed[s][n*384 + {q,k,v}] (bf16), float sincos -------------
__global__ __launch_bounds__(256) void rope_kernel(ushort* __restrict__ mixed) {
  int t = blockIdx.x * 256 + threadIdx.x;   // S*NH*64 threads
  int d = t & 63;
  int n = (t >> 6) & (NHEAD - 1);
  int s = t >> 10;
  ushort* base = mixed + (size_t)s * H3 + n * 384;
  float invf = exp2f((float)d * (-13.287712379549449f / 64.0f));
  float ang = (float)s * invf;
  float si, c; sincosf(ang, &si, &c);
  float q0 = bf2f(base[d]),       q1 = bf2f(base[64 + d]);
  float k0 = bf2f(base[128 + d]), k1 = bf2f(base[192 + d]);
  base[d]       = f2bf(q0 * c - q1 * si);
  base[64 + d]  = f2bf(q1 * c + q0 * si);
  base[128 + d] = f2bf(k0 * c - k1 * si);
  base[192 + d] = f2bf(k1 * c + k0 * si);
}

// ---- V transpose: mixed v-part (bf16) -> vt[n][d][s] ------------------------------------
__global__ __launch_bounds__(256) void v_transpose(const ushort* __restrict__ mixed,
                                                   ushort* __restrict__ vt) {
  __shared__ __align__(16) ushort Vl[64 * 136];
  const int tid = threadIdx.x;
  const int sb = blockIdx.x;
  const int n  = blockIdx.y;
#pragma unroll
  for (int it = 0; it < 4; ++it) {
    int c = tid + it * 256;
    int row = c >> 4, dp = (c & 15) * 8;
    *(int4*)&Vl[row * 136 + dp] =
        *(const int4*)&mixed[(size_t)(sb * 64 + row) * H3 + n * 384 + 256 + dp];
  }
  __syncthreads();
#pragma unroll
  for (int it = 0; it < 4; ++it) {
    int c = tid + it * 256;
    int d = c >> 3, sp = (c & 7) * 8;
    union { ushort u[8]; int4 v; } pk;
#pragma unroll
    for (int e = 0; e < 8; ++e) pk.u[e] = Vl[(sp + e) * 136 + d];
    *(int4*)&vt[((size_t)(n * 128 + d)) * S_LEN + sb * 64 + sp] = pk.v;
  }
}

// ---- Flash attention R11: DMA-staged dbuf K + windowed V, XOR-swizzled, bf16 P ----------
__global__ __launch_bounds__(256, 2) void attn_kernel(const ushort* __restrict__ mixed,
                                                      const ushort* __restrict__ vt,
                                                      ushort* __restrict__ ctx,
                                                      int CS, int CH) {
  __shared__ __align__(16) ushort Ks[2][64 * 128];  // DMA dest, linear; chunk^=(row&7) via source
  __shared__ __align__(16) ushort Vs[128 * 64];     // DMA dest, linear; chunk^=(row&7) via source
  __shared__ __align__(16) ushort Ss[4][16 * 72];   // per-wave P (bf16), +8 pad

  const int tid  = threadIdx.x;
  const int lane = tid & 63;
  const int w    = tid >> 6;
  const int quad = lane >> 4, ln15 = lane & 15;
  const int qb = blockIdx.x;
  const int n  = blockIdx.y;
  const float scale = 0.08838834764831845f;

  const ushort* Kg = mixed + n * 384 + 128;
  const ushort* Vg = vt + (size_t)n * 128 * S_LEN;

  // Q fragments (registers, whole kernel)
  bf16x8 aqr[4];
#pragma unroll
  for (int ks = 0; ks < 4; ++ks)
    aqr[ks] = *(const bf16x8*)&mixed[(size_t)(qb * 64 + 16 * w + ln15) * H3 + n * 384
                                     + ks * 32 + quad * 8];

  f32x4 acc_o[8];
#pragma unroll
  for (int jt = 0; jt < 8; ++jt) acc_o[jt] = (f32x4){0.f, 0.f, 0.f, 0.f};
  float m_run[4], l_run[4];
#pragma unroll
  for (int r = 0; r < 4; ++r) { m_run[r] = -1e30f; l_run[r] = 0.0f; }

  ushort* Ssw = Ss[w];

  // DMA geometry. K issue: 1KB = 4 rows x 16 chunks(16B). V issue: 1KB = 8 rows x 8 chunks.
  const int krow = lane >> 4, kcs = lane & 15;
  const int vrow = lane >> 3, vcs = lane & 7;
  const int swz  = ln15 & 7;   // read-side XOR key: (16*jt+ln15)&7 == ln15&7

#define STAGE_K(KT, BUF)                                                        \
  { _Pragma("unroll")                                                           \
    for (int i = 0; i < 4; ++i) {                                               \
      int kr = w * 16 + i * 4 + krow;                                           \
      int kcl = kcs ^ (kr & 7);                                                 \
      async16(&Kg[(size_t)((KT) * 64 + kr) * H3 + kcl * 8],                     \
              &Ks[BUF][(w * 16 + i * 4) * 128]);                                \
    } }
#define STAGE_V(KT)                                                             \
  { _Pragma("unroll")                                                           \
    for (int i = 0; i < 4; ++i) {                                               \
      int vr = w * 32 + i * 8 + vrow;                                           \
      int vcl = vcs ^ (vr & 7);                                                 \
      async16(&Vg[(size_t)vr * S_LEN + (KT) * 64 + vcl * 8],                    \
              &Vs[(w * 32 + i * 8) * 64]);                                      \
    } }

  int cur = 0;
  STAGE_K(0, 0);
  __syncthreads();   // drain: K(0) ready

  for (int kt = 0; kt <= qb; ++kt) {
    // Issue V(kt) and K(kt+1) DMAs; they land by barrier#1 (hidden under QK+softmax).
    STAGE_V(kt);
    if (kt < qb) STAGE_K(kt + 1, cur ^ 1);

    // QK^T from Ks[cur] (swizzled read: conflict-free)
    f32x4 sacc[4];
#pragma unroll
    for (int jt = 0; jt < 4; ++jt) sacc[jt] = (f32x4){0.f, 0.f, 0.f, 0.f};
#pragma unroll
    for (int ks = 0; ks < 4; ++ks) {
#pragma unroll
      for (int jt = 0; jt < 4; ++jt) {
        bf16x8 bk = *(const bf16x8*)&Ks[cur][(16 * jt + ln15) * 128
                                            + ((ks * 4 + quad) ^ swz) * 8];
        sacc[jt] = __builtin_amdgcn_mfma_f32_16x16x32_bf16(aqr[ks], bk, sacc[jt], 0, 0, 0);
      }
    }

    // mask + online softmax
    float sv[4][4];
    const int ig = qb * 64 + 16 * w + 4 * quad;
#pragma unroll
    for (int jt = 0; jt < 4; ++jt) {
      int jg = kt * 64 + 16 * jt + ln15;
#pragma unroll
      for (int r = 0; r < 4; ++r) {
        float x = sacc[jt][r] * scale;
        sv[jt][r] = (jg > ig + r) ? -10000.0f : x;
      }
    }

    float tmx[4];
#pragma unroll
    for (int r = 0; r < 4; ++r)
      tmx[r] = fmaxf(fmaxf(sv[0][r], sv[1][r]), fmaxf(sv[2][r], sv[3][r]));
#pragma unroll
    for (int m = 1; m <= 8; m <<= 1)
#pragma unroll
      for (int r = 0; r < 4; ++r) tmx[r] = fmaxf(tmx[r], __shfl_xor(tmx[r], m));

    float alpha[4];
#pragma unroll
    for (int r = 0; r < 4; ++r) {
      float m_new = fmaxf(m_run[r], tmx[r]);
      alpha[r] = __expf(m_run[r] - m_new);
      m_run[r] = m_new;
    }

    // P -> bf16 LDS (wave-local), row-sum
    float ps[4] = {0.f, 0.f, 0.f, 0.f};
#pragma unroll
    for (int jt = 0; jt < 4; ++jt)
#pragma unroll
      for (int r = 0; r < 4; ++r) {
        float p = __expf(sv[jt][r] - m_run[r]);
        Ssw[(4 * quad + r) * 72 + 16 * jt + ln15] = f2bf(p);
        ps[r] += p;
      }
#pragma unroll
    for (int m = 1; m <= 8; m <<= 1)
#pragma unroll
      for (int r = 0; r < 4; ++r) ps[r] += __shfl_xor(ps[r], m);
#pragma unroll
    for (int r = 0; r < 4; ++r) l_run[r] = alpha[r] * l_run[r] + ps[r];

    // rescale O
#pragma unroll
    for (int jt = 0; jt < 8; ++jt)
#pragma unroll
      for (int r = 0; r < 4; ++r) acc_o[jt][r] *= alpha[r];

    __syncthreads();   // barrier#1: vmcnt drained -> V(kt) and K(kt+1) landed

    // PV: P direct bf16 from LDS, V swizzled read
#pragma unroll
    for (int ks = 0; ks < 2; ++ks) {
      bf16x8 ap = *(const bf16x8*)&Ssw[ln15 * 72 + ks * 32 + quad * 8];
#pragma unroll
      for (int jt = 0; jt < 8; ++jt) {
        bf16x8 bv = *(const bf16x8*)&Vs[(16 * jt + ln15) * 64
                                        + ((ks * 4 + quad) ^ swz) * 8];
        acc_o[jt] = __builtin_amdgcn_mfma_f32_16x16x32_bf16(ap, bv, acc_o[jt], 0, 0, 0);
      }
    }

    __syncthreads();   // barrier#2: Vs fully consumed -> next iter's V DMA may overwrite
    cur ^= 1;
  }
#undef STAGE_K
#undef STAGE_V

  float rinv[4];
#pragma unroll
  for (int r = 0; r < 4; ++r) rinv[r] = 1.0f / l_run[r];
#pragma unroll
  for (int jt = 0; jt < 8; ++jt)
#pragma unroll
    for (int r = 0; r < 4; ++r) {
      int row = qb * 64 + 16 * w + 4 * quad + r;
      int col = 16 * jt + ln15;
      ctx[(size_t)row * CS + n * CH + col] = f2bf(acc_o[jt][r] * rinv[r]);
    }
}

// ---- launch ------------------------------------------------------------------------------
extern "C" void kernel_launch(void* const* d_in, const int* in_sizes, int n_in,
                              void* d_out, int out_size, void* d_ws, size_t ws_size,
                              hipStream_t stream) {
  const float* hidden  = (const float*)d_in[0];
  const float* w_qkv   = (const float*)d_in[2];
  const float* b_qkv   = (const float*)d_in[3];
  const float* w_dense = (const float*)d_in[4];
  float* out = (float*)d_out;

  char* ws = (char*)d_ws;

  const size_t wq_b    = (size_t)H3 * HID * 2;             // 25,165,824
  const size_t h_b     = (size_t)S_LEN * HID * 2;          //  8,388,608
  const size_t mixed_b = (size_t)S_LEN * H3 * 2;           // 25,165,824
  const size_t vt_b    = (size_t)NHEAD * HDIM * S_LEN * 2; //  8,388,608
  const size_t fast_need = wq_b + h_b + mixed_b + vt_b;    // 67,108,864 (64 MiB)

  if (ws_size >= fast_need) {
    // fast path: bf16 pre-convert + async-staged GEMMs
    ushort* WQ    = (ushort*)ws;                       // w_qkv bf16 (WD reuses this later)
    ushort* Hbf   = (ushort*)(ws + wq_b);
    ushort* mixed = (ushort*)(ws + wq_b + h_b);
    ushort* vt    = (ushort*)(ws + wq_b + h_b + mixed_b);
    ushort* WD    = WQ;                                // w_qkv dead after QKV GEMM
    ushort* ctx   = mixed;                             // q-slots of mixed (race-free)

    cvt_bf16<<<2048, 256, 0, stream>>>(hidden, Hbf, S_LEN * HID / 8);
    cvt_bf16<<<6144, 256, 0, stream>>>(w_qkv, WQ, H3 * HID / 8);
    gemm_async<128, 128, true, false><<<dim3(48, 16), 256, 0, stream>>>(
        Hbf, WQ, b_qkv, mixed, H3, HID, HID, 128);
    rope_kernel<<<8192, 256, 0, stream>>>(mixed);
    v_transpose<<<dim3(32, 16), 256, 0, stream>>>(mixed, vt);
    attn_kernel<<<dim3(32, 16), 256, 0, stream>>>(mixed, vt, ctx, H3, 384);
    cvt_bf16<<<2048, 256, 0, stream>>>(w_dense, WD, HID * HID / 8);
    gemm_async<64, 128, false, true><<<dim3(16, 32), 256, 0, stream>>>(
        ctx, WD, nullptr, out, HID, HID, H3, 384);
  } else {
    // fallback: round-4 proven path
    ushort* mixed = (ushort*)ws;
    ushort* vt    = (ushort*)(ws + mixed_b);
    const bool big = ws_size >= mixed_b + vt_b + (size_t)S_LEN * HID * 2;
    ushort* ctx = big ? (ushort*)(ws + mixed_b + vt_b) : mixed;
    const int CS = big ? HID  : H3;
    const int CH = big ? HDIM : 384;

    gemm_bt<true, true, false><<<dim3(48, 16), 256, 0, stream>>>(
        hidden, w_qkv, b_qkv, mixed, S_LEN, H3, HID, HID, HDIM);
    rope_kernel<<<8192, 256, 0, stream>>>(mixed);
    v_transpose<<<dim3(32, 16), 256, 0, stream>>>(mixed, vt);
    attn_kernel<<<dim3(32, 16), 256, 0, stream>>>(mixed, vt, ctx, CS, CH);
    gemm_bt<false, false, true><<<dim3(16, 16), 256, 0, stream>>>(
        ctx, w_dense, nullptr, out, S_LEN, HID, HID, CS, CH);
  }
}

// Round 8
// 323.729 us; speedup vs baseline: 1.3566x; 1.0661x over previous
//
#include <hip/hip_runtime.h>

// ParallelSelfAttention: S=2048 B=1 H=2048 NH=16 HD=128. I/O f32, internal bf16 MFMA.
// R12 = R11 (DMA-staged dbuf K + windowed V, both-sides XOR swizzle) + swapped-operand
// QK^T with permuted K row staging. mfma(K,Q) puts a full q-row per lane (q=ln15);
// K rows staged in order sigma(jt*16+4q+r)=((jt&2)<<4)+8q+((jt&1)<<2)+r so each lane's
// 16 P-values ARE its PV A-fragment (k=8*quad+j / 32+8*quad+j) -> P packs in-register:
// no P LDS round-trip, softmax reduce 32 shfl -> 4, Ss deleted -> LDS 49152 -> 3 blocks/CU.

#define S_LEN 2048
#define NHEAD 16
#define HDIM  128
#define HID   2048
#define H3    6144

typedef short bf16x8 __attribute__((ext_vector_type(8)));
typedef float f32x4  __attribute__((ext_vector_type(4)));

__device__ __forceinline__ float bf2f(ushort u) {
  union { float f; unsigned int i; } v; v.i = ((unsigned int)u) << 16; return v.f;
}
__device__ __forceinline__ ushort f2bf(float f) {
  union { float f; unsigned int i; } v; v.f = f;
  unsigned int r = v.i + 0x7fffu + ((v.i >> 16) & 1u);
  return (ushort)(r >> 16);
}
__device__ __forceinline__ int4 cvt8(const float* p) {
  float4 a = *(const float4*)p, b = *(const float4*)(p + 4);
  union { ushort u[8]; int4 v; } r;
  r.u[0] = f2bf(a.x); r.u[1] = f2bf(a.y); r.u[2] = f2bf(a.z); r.u[3] = f2bf(a.w);
  r.u[4] = f2bf(b.x); r.u[5] = f2bf(b.y); r.u[6] = f2bf(b.z); r.u[7] = f2bf(b.w);
  return r.v;
}

// async global->LDS DMA, 16B per lane; LDS dest = wave-uniform base + lane*16
typedef __attribute__((address_space(1))) const unsigned int gu32;
typedef __attribute__((address_space(3))) unsigned int lu32;
__device__ __forceinline__ void async16(const void* g, void* l) {
  __builtin_amdgcn_global_load_lds((gu32*)g, (lu32*)l, 16, 0, 0);
}

// ---- f32 -> bf16 elementwise convert (8 elems/thread) -----------------------------------
__global__ __launch_bounds__(256) void cvt_bf16(const float* __restrict__ src,
                                                ushort* __restrict__ dst, int n8) {
  int i = blockIdx.x * 256 + threadIdx.x;
  if (i < n8) *(int4*)&dst[(size_t)i * 8] = cvt8(&src[(size_t)i * 8]);
}

// ---- Fast GEMM: C[M,N] = A @ W^T (+bias). A,W bf16; staging via global_load_lds. --------
template<int BM, int BN, bool HAS_BIAS, bool OUT_F32>
__global__ __launch_bounds__(256) void gemm_async(const ushort* __restrict__ A,
                                                  const ushort* __restrict__ W,
                                                  const float* __restrict__ bias,
                                                  void* __restrict__ Cv,
                                                  int N, int K, int AS, int AH) {
  __shared__ __align__(16) ushort As[BM * 32];
  __shared__ __align__(16) ushort Ws[BN * 32];
  const int tid  = threadIdx.x;
  const int lane = tid & 63;
  const int w    = tid >> 6;
  const int wr   = w >> 1, wc = w & 1;
  const int quad = lane >> 4, ln15 = lane & 15;
  const int tm = blockIdx.y * BM, tn = blockIdx.x * BN;
  constexpr int MI = BM / 32, NJ = BN / 32;

  f32x4 acc[MI][NJ];
#pragma unroll
  for (int i = 0; i < MI; ++i)
#pragma unroll
    for (int j = 0; j < NJ; ++j) acc[i][j] = (f32x4){0.f, 0.f, 0.f, 0.f};

  const int lrow = lane >> 2;          // 0..15 within a 16-row issue
  const int lcol = (lane & 3) * 8;     // k element offset within 32-chunk

  for (int k0 = 0; k0 < K; k0 += 32) {
    const int aoff = (k0 >> 7) * AH + (k0 & 127) + lcol;
    for (int r = w; r < (BM + BN) / 16; r += 4) {
      if (r < BM / 16) {
        async16(&A[(size_t)(tm + r * 16 + lrow) * AS + aoff], &As[r * 16 * 32]);
      } else {
        const int rb = r - BM / 16;
        async16(&W[(size_t)(tn + rb * 16 + lrow) * K + k0 + lcol], &Ws[rb * 16 * 32]);
      }
    }
    __syncthreads();
    bf16x8 af[MI], bw[NJ];
#pragma unroll
    for (int i = 0; i < MI; ++i)
      af[i] = *(const bf16x8*)&As[((BM / 2) * wr + 16 * i + ln15) * 32 + quad * 8];
#pragma unroll
    for (int j = 0; j < NJ; ++j)
      bw[j] = *(const bf16x8*)&Ws[((BN / 2) * wc + 16 * j + ln15) * 32 + quad * 8];
#pragma unroll
    for (int i = 0; i < MI; ++i)
#pragma unroll
      for (int j = 0; j < NJ; ++j)
        acc[i][j] = __builtin_amdgcn_mfma_f32_16x16x32_bf16(af[i], bw[j], acc[i][j], 0, 0, 0);
    __syncthreads();
  }

#pragma unroll
  for (int i = 0; i < MI; ++i)
#pragma unroll
    for (int j = 0; j < NJ; ++j) {
      int col = tn + (BN / 2) * wc + 16 * j + ln15;
      float badd = HAS_BIAS ? bias[col] : 0.0f;
#pragma unroll
      for (int r = 0; r < 4; ++r) {
        int row = tm + (BM / 2) * wr + 16 * i + 4 * quad + r;
        float val = acc[i][j][r] + badd;
        if (OUT_F32) ((float*)Cv)[(size_t)row * N + col] = val;
        else         ((ushort*)Cv)[(size_t)row * N + col] = f2bf(val);
      }
    }
}

// ---- Fallback GEMM (round-4 proven): A f32-or-bf16, W f32, cvt in staging ---------------
template<bool A_F32, bool HAS_BIAS, bool OUT_F32>
__global__ __launch_bounds__(256) void gemm_bt(const void* __restrict__ Av,
                                               const float* __restrict__ W,
                                               const float* __restrict__ bias,
                                               void* __restrict__ Cv,
                                               int M, int N, int K, int AS, int AH) {
  __shared__ __align__(16) ushort As[128 * 40];
  __shared__ __align__(16) ushort Ws[128 * 40];
  const int tid  = threadIdx.x;
  const int lane = tid & 63;
  const int w    = tid >> 6;
  const int wr   = w >> 1, wc = w & 1;
  const int quad = lane >> 4, ln15 = lane & 15;
  const int tm = blockIdx.y * 128, tn = blockIdx.x * 128;

  f32x4 acc[4][4];
#pragma unroll
  for (int i = 0; i < 4; ++i)
#pragma unroll
    for (int j = 0; j < 4; ++j) acc[i][j] = (f32x4){0.f, 0.f, 0.f, 0.f};

  const int row0 = tid >> 2, row1 = row0 + 64;
  const int kp   = (tid & 3) * 8;

  for (int k0 = 0; k0 < K; k0 += 32) {
    const int ka   = k0 + kp;
    const int aoff = (ka >> 7) * AH + (ka & 127);
    if (A_F32) {
      const float* A = (const float*)Av;
      *(int4*)&As[row0 * 40 + kp] = cvt8(&A[(size_t)(tm + row0) * AS + aoff]);
      *(int4*)&As[row1 * 40 + kp] = cvt8(&A[(size_t)(tm + row1) * AS + aoff]);
    } else {
      const ushort* A = (const ushort*)Av;
      *(int4*)&As[row0 * 40 + kp] = *(const int4*)&A[(size_t)(tm + row0) * AS + aoff];
      *(int4*)&As[row1 * 40 + kp] = *(const int4*)&A[(size_t)(tm + row1) * AS + aoff];
    }
    *(int4*)&Ws[row0 * 40 + kp] = cvt8(&W[(size_t)(tn + row0) * K + ka]);
    *(int4*)&Ws[row1 * 40 + kp] = cvt8(&W[(size_t)(tn + row1) * K + ka]);
    __syncthreads();
    bf16x8 af[4], bw[4];
#pragma unroll
    for (int i = 0; i < 4; ++i)
      af[i] = *(const bf16x8*)&As[(64 * wr + 16 * i + ln15) * 40 + quad * 8];
#pragma unroll
    for (int j = 0; j < 4; ++j)
      bw[j] = *(const bf16x8*)&Ws[(64 * wc + 16 * j + ln15) * 40 + quad * 8];
#pragma unroll
    for (int i = 0; i < 4; ++i)
#pragma unroll
      for (int j = 0; j < 4; ++j)
        acc[i][j] = __builtin_amdgcn_mfma_f32_16x16x32_bf16(af[i], bw[j], acc[i][j], 0, 0, 0);
    __syncthreads();
  }

#pragma unroll
  for (int i = 0; i < 4; ++i)
#pragma unroll
    for (int j = 0; j < 4; ++j) {
      int col = tn + 64 * wc + 16 * j + ln15;
      float badd = HAS_BIAS ? bias[col] : 0.0f;
#pragma unroll
      for (int r = 0; r < 4; ++r) {
        int row = tm + 64 * wr + 16 * i + 4 * quad + r;
        float val = acc[i][j][r] + badd;
        if (OUT_F32) ((float*)Cv)[(size_t)row * N + col] = val;
        else         ((ushort*)Cv)[(size_t)row * N + col] = f2bf(val);
      }
    }
}

// ---- RoPE in place on q,k of mixed[s][n*384 + {q,k,v}] (bf16), float sincos -------------
__global__ __launch_bounds__(256) void rope_kernel(ushort* __restrict__ mixed) {
  int t = blockIdx.x * 256 + threadIdx.x;   // S*NH*64 threads
  int d = t & 63;
  int n = (t >> 6) & (NHEAD - 1);
  int s = t >> 10;
  ushort* base = mixed + (size_t)s * H3 + n * 384;
  float invf = exp2f((float)d * (-13.287712379549449f / 64.0f));
  float ang = (float)s * invf;
  float si, c; sincosf(ang, &si, &c);
  float q0 = bf2f(base[d]),       q1 = bf2f(base[64 + d]);
  float k0 = bf2f(base[128 + d]), k1 = bf2f(base[192 + d]);
  base[d]       = f2bf(q0 * c - q1 * si);
  base[64 + d]  = f2bf(q1 * c + q0 * si);
  base[128 + d] = f2bf(k0 * c - k1 * si);
  base[192 + d] = f2bf(k1 * c + k0 * si);
}

// ---- V transpose: mixed v-part (bf16) -> vt[n][d][s] ------------------------------------
__global__ __launch_bounds__(256) void v_transpose(const ushort* __restrict__ mixed,
                                                   ushort* __restrict__ vt) {
  __shared__ __align__(16) ushort Vl[64 * 136];
  const int tid = threadIdx.x;
  const int sb = blockIdx.x;
  const int n  = blockIdx.y;
#pragma unroll
  for (int it = 0; it < 4; ++it) {
    int c = tid + it * 256;
    int row = c >> 4, dp = (c & 15) * 8;
    *(int4*)&Vl[row * 136 + dp] =
        *(const int4*)&mixed[(size_t)(sb * 64 + row) * H3 + n * 384 + 256 + dp];
  }
  __syncthreads();
#pragma unroll
  for (int it = 0; it < 4; ++it) {
    int c = tid + it * 256;
    int d = c >> 3, sp = (c & 7) * 8;
    union { ushort u[8]; int4 v; } pk;
#pragma unroll
    for (int e = 0; e < 8; ++e) pk.u[e] = Vl[(sp + e) * 136 + d];
    *(int4*)&vt[((size_t)(n * 128 + d)) * S_LEN + sb * 64 + sp] = pk.v;
  }
}

// ---- Flash attention R12: swapped QK^T + permuted K staging, in-register P --------------
__global__ __launch_bounds__(256, 3) void attn_kernel(const ushort* __restrict__ mixed,
                                                      const ushort* __restrict__ vt,
                                                      ushort* __restrict__ ctx,
                                                      int CS, int CH) {
  __shared__ __align__(16) ushort Ks[2][64 * 128];  // DMA dest; rows PERMUTED by sigma
  __shared__ __align__(16) ushort Vs[128 * 64];     // DMA dest; chunk^=(row&7) via source

  const int tid  = threadIdx.x;
  const int lane = tid & 63;
  const int w    = tid >> 6;
  const int quad = lane >> 4, ln15 = lane & 15;
  const int qb = blockIdx.x;
  const int n  = blockIdx.y;
  const float scale = 0.08838834764831845f;

  const ushort* Kg = mixed + n * 384 + 128;
  const ushort* Vg = vt + (size_t)n * 128 * S_LEN;

  // Q fragments (registers, whole kernel); lane holds Q row (16w+ln15), d = ks*32+quad*8..
  bf16x8 aqr[4];
#pragma unroll
  for (int ks = 0; ks < 4; ++ks)
    aqr[ks] = *(const bf16x8*)&mixed[(size_t)(qb * 64 + 16 * w + ln15) * H3 + n * 384
                                     + ks * 32 + quad * 8];

  f32x4 acc_o[8];
#pragma unroll
  for (int jt = 0; jt < 8; ++jt) acc_o[jt] = (f32x4){0.f, 0.f, 0.f, 0.f};
  float m_run = -1e30f, l_run = 0.0f;   // scalar: lane owns q = 16w + ln15

  // DMA geometry. K issue: 1KB = 4 rows x 16 chunks(16B). V issue: 1KB = 8 rows x 8 chunks.
  const int krow = lane >> 4, kcs = lane & 15;
  const int vrow = lane >> 3, vcs = lane & 7;
  const int swz  = ln15 & 7;   // read-side XOR key (LDS row & 7)

  // K row permutation: LDS row rho = w*16 + i*4 + krow holds global k-row
  //   sigma(rho) = ((w&2)<<4) + 8*i + ((w&1)<<2) + krow   (jt=w, q=i, r=krow)
  // so that after swapped-QKT, lane (ln15,quad)'s P values at (jt,r) are
  //   k = ((jt&2)<<4) + 8*quad + ((jt&1)<<2) + r  -> ap packs with zero shuffles.
#define STAGE_K(KT, BUF)                                                        \
  { _Pragma("unroll")                                                           \
    for (int i = 0; i < 4; ++i) {                                               \
      int sig = ((w & 2) << 4) + 8 * i + ((w & 1) << 2) + krow;                 \
      int kcl = kcs ^ ((i * 4 + krow) & 7);                                     \
      async16(&Kg[(size_t)((KT) * 64 + sig) * H3 + kcl * 8],                    \
              &Ks[BUF][(w * 16 + i * 4) * 128]);                                \
    } }
#define STAGE_V(KT)                                                             \
  { _Pragma("unroll")                                                           \
    for (int i = 0; i < 4; ++i) {                                               \
      int vr = w * 32 + i * 8 + vrow;                                           \
      int vcl = vcs ^ (vr & 7);                                                 \
      async16(&Vg[(size_t)vr * S_LEN + (KT) * 64 + vcl * 8],                    \
              &Vs[(w * 32 + i * 8) * 64]);                                      \
    } }

  int cur = 0;
  STAGE_K(0, 0);
  __syncthreads();   // drain: K(0) ready

  const int ig = qb * 64 + 16 * w + ln15;   // this lane's global q row

  for (int kt = 0; kt <= qb; ++kt) {
    // Issue V(kt) and K(kt+1) DMAs; they land by barrier#1 (hidden under QK+softmax).
    STAGE_V(kt);
    if (kt < qb) STAGE_K(kt + 1, cur ^ 1);

    // Swapped QK^T: mfma(K, Q) -> sacc[jt][r] = S[k = sigma(jt,4quad+r)][q = ln15]
    f32x4 sacc[4];
#pragma unroll
    for (int jt = 0; jt < 4; ++jt) sacc[jt] = (f32x4){0.f, 0.f, 0.f, 0.f};
#pragma unroll
    for (int ks = 0; ks < 4; ++ks) {
#pragma unroll
      for (int jt = 0; jt < 4; ++jt) {
        bf16x8 bk = *(const bf16x8*)&Ks[cur][(16 * jt + ln15) * 128
                                            + ((ks * 4 + quad) ^ swz) * 8];
        sacc[jt] = __builtin_amdgcn_mfma_f32_16x16x32_bf16(bk, aqr[ks], sacc[jt], 0, 0, 0);
      }
    }

    // mask (k local index = sigma-permuted) + scalar online softmax
    float sv[4][4];
#pragma unroll
    for (int jt = 0; jt < 4; ++jt) {
#pragma unroll
      for (int r = 0; r < 4; ++r) {
        int kl = ((jt & 2) << 4) + 8 * quad + ((jt & 1) << 2) + r;
        int jg = kt * 64 + kl;
        float x = sacc[jt][r] * scale;
        sv[jt][r] = (jg > ig) ? -10000.0f : x;
      }
    }

    float tmx = sv[0][0];
#pragma unroll
    for (int jt = 0; jt < 4; ++jt)
#pragma unroll
      for (int r = 0; r < 4; ++r) tmx = fmaxf(tmx, sv[jt][r]);
    tmx = fmaxf(tmx, __shfl_xor(tmx, 16));
    tmx = fmaxf(tmx, __shfl_xor(tmx, 32));

    float m_new = fmaxf(m_run, tmx);
    float alpha = __expf(m_run - m_new);
    m_run = m_new;

    float p[4][4];
    float ps = 0.0f;
#pragma unroll
    for (int jt = 0; jt < 4; ++jt)
#pragma unroll
      for (int r = 0; r < 4; ++r) {
        p[jt][r] = __expf(sv[jt][r] - m_run);
        ps += p[jt][r];
      }
    ps += __shfl_xor(ps, 16);
    ps += __shfl_xor(ps, 32);
    l_run = alpha * l_run + ps;

    // broadcast alpha to acc_o's row layout (q = 4*quad + r) and rescale O
    float aw[4];
#pragma unroll
    for (int r = 0; r < 4; ++r) aw[r] = __shfl(alpha, 4 * quad + r);
#pragma unroll
    for (int jt = 0; jt < 8; ++jt)
#pragma unroll
      for (int r = 0; r < 4; ++r) acc_o[jt][r] *= aw[r];

    // pack P -> PV A-fragments in-register (k = 8*quad+j for ap0, 32+8*quad+j for ap1)
    bf16x8 ap0, ap1;
#pragma unroll
    for (int j = 0; j < 4; ++j) {
      ap0[j]     = (short)f2bf(p[0][j]);
      ap0[4 + j] = (short)f2bf(p[1][j]);
      ap1[j]     = (short)f2bf(p[2][j]);
      ap1[4 + j] = (short)f2bf(p[3][j]);
    }

    __syncthreads();   // barrier#1: vmcnt drained -> V(kt) and K(kt+1) landed

    // PV: A = in-register P, V swizzled read from LDS
#pragma unroll
    for (int jt = 0; jt < 8; ++jt) {
      bf16x8 bv0 = *(const bf16x8*)&Vs[(16 * jt + ln15) * 64 + ((quad) ^ swz) * 8];
      acc_o[jt] = __builtin_amdgcn_mfma_f32_16x16x32_bf16(ap0, bv0, acc_o[jt], 0, 0, 0);
      bf16x8 bv1 = *(const bf16x8*)&Vs[(16 * jt + ln15) * 64 + ((4 + quad) ^ swz) * 8];
      acc_o[jt] = __builtin_amdgcn_mfma_f32_16x16x32_bf16(ap1, bv1, acc_o[jt], 0, 0, 0);
    }

    __syncthreads();   // barrier#2: Vs fully consumed -> next iter's V DMA may overwrite
    cur ^= 1;
  }
#undef STAGE_K
#undef STAGE_V

  // redistribute l_run (per-lane q=ln15) to output row layout (q = 4*quad + r)
  float rinv[4];
#pragma unroll
  for (int r = 0; r < 4; ++r) rinv[r] = 1.0f / __shfl(l_run, 4 * quad + r);
#pragma unroll
  for (int jt = 0; jt < 8; ++jt)
#pragma unroll
    for (int r = 0; r < 4; ++r) {
      int row = qb * 64 + 16 * w + 4 * quad + r;
      int col = 16 * jt + ln15;
      ctx[(size_t)row * CS + n * CH + col] = f2bf(acc_o[jt][r] * rinv[r]);
    }
}

// ---- launch ------------------------------------------------------------------------------
extern "C" void kernel_launch(void* const* d_in, const int* in_sizes, int n_in,
                              void* d_out, int out_size, void* d_ws, size_t ws_size,
                              hipStream_t stream) {
  const float* hidden  = (const float*)d_in[0];
  const float* w_qkv   = (const float*)d_in[2];
  const float* b_qkv   = (const float*)d_in[3];
  const float* w_dense = (const float*)d_in[4];
  float* out = (float*)d_out;

  char* ws = (char*)d_ws;

  const size_t wq_b    = (size_t)H3 * HID * 2;             // 25,165,824
  const size_t h_b     = (size_t)S_LEN * HID * 2;          //  8,388,608
  const size_t mixed_b = (size_t)S_LEN * H3 * 2;           // 25,165,824
  const size_t vt_b    = (size_t)NHEAD * HDIM * S_LEN * 2; //  8,388,608
  const size_t fast_need = wq_b + h_b + mixed_b + vt_b;    // 67,108,864 (64 MiB)

  if (ws_size >= fast_need) {
    // fast path: bf16 pre-convert + async-staged GEMMs
    ushort* WQ    = (ushort*)ws;                       // w_qkv bf16 (WD reuses this later)
    ushort* Hbf   = (ushort*)(ws + wq_b);
    ushort* mixed = (ushort*)(ws + wq_b + h_b);
    ushort* vt    = (ushort*)(ws + wq_b + h_b + mixed_b);
    ushort* WD    = WQ;                                // w_qkv dead after QKV GEMM
    ushort* ctx   = mixed;                             // q-slots of mixed (race-free)

    cvt_bf16<<<2048, 256, 0, stream>>>(hidden, Hbf, S_LEN * HID / 8);
    cvt_bf16<<<6144, 256, 0, stream>>>(w_qkv, WQ, H3 * HID / 8);
    gemm_async<128, 128, true, false><<<dim3(48, 16), 256, 0, stream>>>(
        Hbf, WQ, b_qkv, mixed, H3, HID, HID, 128);
    rope_kernel<<<8192, 256, 0, stream>>>(mixed);
    v_transpose<<<dim3(32, 16), 256, 0, stream>>>(mixed, vt);
    attn_kernel<<<dim3(32, 16), 256, 0, stream>>>(mixed, vt, ctx, H3, 384);
    cvt_bf16<<<2048, 256, 0, stream>>>(w_dense, WD, HID * HID / 8);
    gemm_async<64, 128, false, true><<<dim3(16, 32), 256, 0, stream>>>(
        ctx, WD, nullptr, out, HID, HID, H3, 384);
  } else {
    // fallback: round-4 proven path
    ushort* mixed = (ushort*)ws;
    ushort* vt    = (ushort*)(ws + mixed_b);
    const bool big = ws_size >= mixed_b + vt_b + (size_t)S_LEN * HID * 2;
    ushort* ctx = big ? (ushort*)(ws + mixed_b + vt_b) : mixed;
    const int CS = big ? HID  : H3;
    const int CH = big ? HDIM : 384;

    gemm_bt<true, true, false><<<dim3(48, 16), 256, 0, stream>>>(
        hidden, w_qkv, b_qkv, mixed, S_LEN, H3, HID, HID, HDIM);
    rope_kernel<<<8192, 256, 0, stream>>>(mixed);
    v_transpose<<<dim3(32, 16), 256, 0, stream>>>(mixed, vt);
    attn_kernel<<<dim3(32, 16), 256, 0, stream>>>(mixed, vt, ctx, CS, CH);
    gemm_bt<false, false, true><<<dim3(16, 16), 256, 0, stream>>>(
        ctx, w_dense, nullptr, out, S_LEN, HID, HID, CS, CH);
  }
}

// Round 9
// 300.584 us; speedup vs baseline: 1.4611x; 1.0770x over previous
//
#include <hip/hip_runtime.h>

// ParallelSelfAttention: S=2048 B=1 H=2048 NH=16 HD=128. I/O f32, internal bf16 MFMA.
// R13 = R12 (attn: swapped QK^T, in-register P, DMA dbuf staging) + gemm_async rebuilt:
// BK=64 (halves K-loop barrier drains, 2x MFMA per staging phase) with rule-21 both-sides
// XOR swizzle: DMA source chunk g = lc8 ^ lrow8 (LDS dest stays linear), fragment read
// slot (kk*4+quad)^(ln15&7). Kills the quarter-wave 8-bank read conflicts (6.29M counter)
// that a 128B row stride would otherwise make 16-way. LDS 32KB/24KB, occupancy unchanged.

#define S_LEN 2048
#define NHEAD 16
#define HDIM  128
#define HID   2048
#define H3    6144

typedef short bf16x8 __attribute__((ext_vector_type(8)));
typedef float f32x4  __attribute__((ext_vector_type(4)));

__device__ __forceinline__ float bf2f(ushort u) {
  union { float f; unsigned int i; } v; v.i = ((unsigned int)u) << 16; return v.f;
}
__device__ __forceinline__ ushort f2bf(float f) {
  union { float f; unsigned int i; } v; v.f = f;
  unsigned int r = v.i + 0x7fffu + ((v.i >> 16) & 1u);
  return (ushort)(r >> 16);
}
__device__ __forceinline__ int4 cvt8(const float* p) {
  float4 a = *(const float4*)p, b = *(const float4*)(p + 4);
  union { ushort u[8]; int4 v; } r;
  r.u[0] = f2bf(a.x); r.u[1] = f2bf(a.y); r.u[2] = f2bf(a.z); r.u[3] = f2bf(a.w);
  r.u[4] = f2bf(b.x); r.u[5] = f2bf(b.y); r.u[6] = f2bf(b.z); r.u[7] = f2bf(b.w);
  return r.v;
}

// async global->LDS DMA, 16B per lane; LDS dest = wave-uniform base + lane*16
typedef __attribute__((address_space(1))) const unsigned int gu32;
typedef __attribute__((address_space(3))) unsigned int lu32;
__device__ __forceinline__ void async16(const void* g, void* l) {
  __builtin_amdgcn_global_load_lds((gu32*)g, (lu32*)l, 16, 0, 0);
}

// ---- f32 -> bf16 elementwise convert (8 elems/thread) -----------------------------------
__global__ __launch_bounds__(256) void cvt_bf16(const float* __restrict__ src,
                                                ushort* __restrict__ dst, int n8) {
  int i = blockIdx.x * 256 + threadIdx.x;
  if (i < n8) *(int4*)&dst[(size_t)i * 8] = cvt8(&src[(size_t)i * 8]);
}

// ---- Fast GEMM: C[M,N] = A @ W^T (+bias). A,W bf16; BK=64, swizzled DMA staging. --------
// A element (row,k) at A[row*AS + (k>>7)*AH + (k&127)]. Block tile BM x BN, 4 waves 2x2.
// LDS rows 64 shorts (128B); slot s of row R holds global chunk s^(R&7) (source-swizzled;
// DMA dest linear). Fragment read: slot (kk*4+quad)^(ln15&7) -> 2 lanes/bank (free).
template<int BM, int BN, bool HAS_BIAS, bool OUT_F32>
__global__ __launch_bounds__(256) void gemm_async(const ushort* __restrict__ A,
                                                  const ushort* __restrict__ W,
                                                  const float* __restrict__ bias,
                                                  void* __restrict__ Cv,
                                                  int N, int K, int AS, int AH) {
  __shared__ __align__(16) ushort As[BM * 64];
  __shared__ __align__(16) ushort Ws[BN * 64];
  const int tid  = threadIdx.x;
  const int lane = tid & 63;
  const int w    = tid >> 6;
  const int wr   = w >> 1, wc = w & 1;
  const int quad = lane >> 4, ln15 = lane & 15;
  const int tm = blockIdx.y * BM, tn = blockIdx.x * BN;
  constexpr int MI = BM / 32, NJ = BN / 32;

  f32x4 acc[MI][NJ];
#pragma unroll
  for (int i = 0; i < MI; ++i)
#pragma unroll
    for (int j = 0; j < NJ; ++j) acc[i][j] = (f32x4){0.f, 0.f, 0.f, 0.f};

  const int lrow8 = lane >> 3;            // row within an 8-row issue block
  const int gsw   = (lane & 7) ^ lrow8;   // pre-swizzled global chunk for this lane
  const int sw    = ln15 & 7;             // read-side XOR key (row&7)

  for (int k0 = 0; k0 < K; k0 += 64) {
    for (int r = w; r < (BM + BN) / 8; r += 4) {
      if (r < BM / 8) {
        const int ka = k0 + gsw * 8;
        async16(&A[(size_t)(tm + r * 8 + lrow8) * AS + (ka >> 7) * AH + (ka & 127)],
                &As[r * 8 * 64]);
      } else {
        const int rb = r - BM / 8;
        async16(&W[(size_t)(tn + rb * 8 + lrow8) * K + k0 + gsw * 8],
                &Ws[rb * 8 * 64]);
      }
    }
    __syncthreads();
#pragma unroll
    for (int kk = 0; kk < 2; ++kk) {
      const int slot = ((kk * 4 + quad) ^ sw) * 8;
      bf16x8 af[MI], bw[NJ];
#pragma unroll
      for (int i = 0; i < MI; ++i)
        af[i] = *(const bf16x8*)&As[((BM / 2) * wr + 16 * i + ln15) * 64 + slot];
#pragma unroll
      for (int j = 0; j < NJ; ++j)
        bw[j] = *(const bf16x8*)&Ws[((BN / 2) * wc + 16 * j + ln15) * 64 + slot];
#pragma unroll
      for (int i = 0; i < MI; ++i)
#pragma unroll
        for (int j = 0; j < NJ; ++j)
          acc[i][j] = __builtin_amdgcn_mfma_f32_16x16x32_bf16(af[i], bw[j], acc[i][j], 0, 0, 0);
    }
    __syncthreads();
  }

#pragma unroll
  for (int i = 0; i < MI; ++i)
#pragma unroll
    for (int j = 0; j < NJ; ++j) {
      int col = tn + (BN / 2) * wc + 16 * j + ln15;
      float badd = HAS_BIAS ? bias[col] : 0.0f;
#pragma unroll
      for (int r = 0; r < 4; ++r) {
        int row = tm + (BM / 2) * wr + 16 * i + 4 * quad + r;
        float val = acc[i][j][r] + badd;
        if (OUT_F32) ((float*)Cv)[(size_t)row * N + col] = val;
        else         ((ushort*)Cv)[(size_t)row * N + col] = f2bf(val);
      }
    }
}

// ---- Fallback GEMM (round-4 proven): A f32-or-bf16, W f32, cvt in staging ---------------
template<bool A_F32, bool HAS_BIAS, bool OUT_F32>
__global__ __launch_bounds__(256) void gemm_bt(const void* __restrict__ Av,
                                               const float* __restrict__ W,
                                               const float* __restrict__ bias,
                                               void* __restrict__ Cv,
                                               int M, int N, int K, int AS, int AH) {
  __shared__ __align__(16) ushort As[128 * 40];
  __shared__ __align__(16) ushort Ws[128 * 40];
  const int tid  = threadIdx.x;
  const int lane = tid & 63;
  const int w    = tid >> 6;
  const int wr   = w >> 1, wc = w & 1;
  const int quad = lane >> 4, ln15 = lane & 15;
  const int tm = blockIdx.y * 128, tn = blockIdx.x * 128;

  f32x4 acc[4][4];
#pragma unroll
  for (int i = 0; i < 4; ++i)
#pragma unroll
    for (int j = 0; j < 4; ++j) acc[i][j] = (f32x4){0.f, 0.f, 0.f, 0.f};

  const int row0 = tid >> 2, row1 = row0 + 64;
  const int kp   = (tid & 3) * 8;

  for (int k0 = 0; k0 < K; k0 += 32) {
    const int ka   = k0 + kp;
    const int aoff = (ka >> 7) * AH + (ka & 127);
    if (A_F32) {
      const float* A = (const float*)Av;
      *(int4*)&As[row0 * 40 + kp] = cvt8(&A[(size_t)(tm + row0) * AS + aoff]);
      *(int4*)&As[row1 * 40 + kp] = cvt8(&A[(size_t)(tm + row1) * AS + aoff]);
    } else {
      const ushort* A = (const ushort*)Av;
      *(int4*)&As[row0 * 40 + kp] = *(const int4*)&A[(size_t)(tm + row0) * AS + aoff];
      *(int4*)&As[row1 * 40 + kp] = *(const int4*)&A[(size_t)(tm + row1) * AS + aoff];
    }
    *(int4*)&Ws[row0 * 40 + kp] = cvt8(&W[(size_t)(tn + row0) * K + ka]);
    *(int4*)&Ws[row1 * 40 + kp] = cvt8(&W[(size_t)(tn + row1) * K + ka]);
    __syncthreads();
    bf16x8 af[4], bw[4];
#pragma unroll
    for (int i = 0; i < 4; ++i)
      af[i] = *(const bf16x8*)&As[(64 * wr + 16 * i + ln15) * 40 + quad * 8];
#pragma unroll
    for (int j = 0; j < 4; ++j)
      bw[j] = *(const bf16x8*)&Ws[(64 * wc + 16 * j + ln15) * 40 + quad * 8];
#pragma unroll
    for (int i = 0; i < 4; ++i)
#pragma unroll
      for (int j = 0; j < 4; ++j)
        acc[i][j] = __builtin_amdgcn_mfma_f32_16x16x32_bf16(af[i], bw[j], acc[i][j], 0, 0, 0);
    __syncthreads();
  }

#pragma unroll
  for (int i = 0; i < 4; ++i)
#pragma unroll
    for (int j = 0; j < 4; ++j) {
      int col = tn + 64 * wc + 16 * j + ln15;
      float badd = HAS_BIAS ? bias[col] : 0.0f;
#pragma unroll
      for (int r = 0; r < 4; ++r) {
        int row = tm + 64 * wr + 16 * i + 4 * quad + r;
        float val = acc[i][j][r] + badd;
        if (OUT_F32) ((float*)Cv)[(size_t)row * N + col] = val;
        else         ((ushort*)Cv)[(size_t)row * N + col] = f2bf(val);
      }
    }
}

// ---- RoPE in place on q,k of mixed[s][n*384 + {q,k,v}] (bf16), float sincos -------------
__global__ __launch_bounds__(256) void rope_kernel(ushort* __restrict__ mixed) {
  int t = blockIdx.x * 256 + threadIdx.x;   // S*NH*64 threads
  int d = t & 63;
  int n = (t >> 6) & (NHEAD - 1);
  int s = t >> 10;
  ushort* base = mixed + (size_t)s * H3 + n * 384;
  float invf = exp2f((float)d * (-13.287712379549449f / 64.0f));
  float ang = (float)s * invf;
  float si, c; sincosf(ang, &si, &c);
  float q0 = bf2f(base[d]),       q1 = bf2f(base[64 + d]);
  float k0 = bf2f(base[128 + d]), k1 = bf2f(base[192 + d]);
  base[d]       = f2bf(q0 * c - q1 * si);
  base[64 + d]  = f2bf(q1 * c + q0 * si);
  base[128 + d] = f2bf(k0 * c - k1 * si);
  base[192 + d] = f2bf(k1 * c + k0 * si);
}

// ---- V transpose: mixed v-part (bf16) -> vt[n][d][s] ------------------------------------
__global__ __launch_bounds__(256) void v_transpose(const ushort* __restrict__ mixed,
                                                   ushort* __restrict__ vt) {
  __shared__ __align__(16) ushort Vl[64 * 136];
  const int tid = threadIdx.x;
  const int sb = blockIdx.x;
  const int n  = blockIdx.y;
#pragma unroll
  for (int it = 0; it < 4; ++it) {
    int c = tid + it * 256;
    int row = c >> 4, dp = (c & 15) * 8;
    *(int4*)&Vl[row * 136 + dp] =
        *(const int4*)&mixed[(size_t)(sb * 64 + row) * H3 + n * 384 + 256 + dp];
  }
  __syncthreads();
#pragma unroll
  for (int it = 0; it < 4; ++it) {
    int c = tid + it * 256;
    int d = c >> 3, sp = (c & 7) * 8;
    union { ushort u[8]; int4 v; } pk;
#pragma unroll
    for (int e = 0; e < 8; ++e) pk.u[e] = Vl[(sp + e) * 136 + d];
    *(int4*)&vt[((size_t)(n * 128 + d)) * S_LEN + sb * 64 + sp] = pk.v;
  }
}

// ---- Flash attention R12: swapped QK^T + permuted K staging, in-register P --------------
__global__ __launch_bounds__(256, 3) void attn_kernel(const ushort* __restrict__ mixed,
                                                      const ushort* __restrict__ vt,
                                                      ushort* __restrict__ ctx,
                                                      int CS, int CH) {
  __shared__ __align__(16) ushort Ks[2][64 * 128];  // DMA dest; rows PERMUTED by sigma
  __shared__ __align__(16) ushort Vs[128 * 64];     // DMA dest; chunk^=(row&7) via source

  const int tid  = threadIdx.x;
  const int lane = tid & 63;
  const int w    = tid >> 6;
  const int quad = lane >> 4, ln15 = lane & 15;
  const int qb = blockIdx.x;
  const int n  = blockIdx.y;
  const float scale = 0.08838834764831845f;

  const ushort* Kg = mixed + n * 384 + 128;
  const ushort* Vg = vt + (size_t)n * 128 * S_LEN;

  // Q fragments (registers, whole kernel); lane holds Q row (16w+ln15), d = ks*32+quad*8..
  bf16x8 aqr[4];
#pragma unroll
  for (int ks = 0; ks < 4; ++ks)
    aqr[ks] = *(const bf16x8*)&mixed[(size_t)(qb * 64 + 16 * w + ln15) * H3 + n * 384
                                     + ks * 32 + quad * 8];

  f32x4 acc_o[8];
#pragma unroll
  for (int jt = 0; jt < 8; ++jt) acc_o[jt] = (f32x4){0.f, 0.f, 0.f, 0.f};
  float m_run = -1e30f, l_run = 0.0f;   // scalar: lane owns q = 16w + ln15

  // DMA geometry. K issue: 1KB = 4 rows x 16 chunks(16B). V issue: 1KB = 8 rows x 8 chunks.
  const int krow = lane >> 4, kcs = lane & 15;
  const int vrow = lane >> 3, vcs = lane & 7;
  const int swz  = ln15 & 7;   // read-side XOR key (LDS row & 7)

  // K row permutation: LDS row rho = w*16 + i*4 + krow holds global k-row
  //   sigma(rho) = ((w&2)<<4) + 8*i + ((w&1)<<2) + krow   (jt=w, q=i, r=krow)
  // so that after swapped-QKT, lane (ln15,quad)'s P values at (jt,r) are
  //   k = ((jt&2)<<4) + 8*quad + ((jt&1)<<2) + r  -> ap packs with zero shuffles.
#define STAGE_K(KT, BUF)                                                        \
  { _Pragma("unroll")                                                           \
    for (int i = 0; i < 4; ++i) {                                               \
      int sig = ((w & 2) << 4) + 8 * i + ((w & 1) << 2) + krow;                 \
      int kcl = kcs ^ ((i * 4 + krow) & 7);                                     \
      async16(&Kg[(size_t)((KT) * 64 + sig) * H3 + kcl * 8],                    \
              &Ks[BUF][(w * 16 + i * 4) * 128]);                                \
    } }
#define STAGE_V(KT)                                                             \
  { _Pragma("unroll")                                                           \
    for (int i = 0; i < 4; ++i) {                                               \
      int vr = w * 32 + i * 8 + vrow;                                           \
      int vcl = vcs ^ (vr & 7);                                                 \
      async16(&Vg[(size_t)vr * S_LEN + (KT) * 64 + vcl * 8],                    \
              &Vs[(w * 32 + i * 8) * 64]);                                      \
    } }

  int cur = 0;
  STAGE_K(0, 0);
  __syncthreads();   // drain: K(0) ready

  const int ig = qb * 64 + 16 * w + ln15;   // this lane's global q row

  for (int kt = 0; kt <= qb; ++kt) {
    // Issue V(kt) and K(kt+1) DMAs; they land by barrier#1 (hidden under QK+softmax).
    STAGE_V(kt);
    if (kt < qb) STAGE_K(kt + 1, cur ^ 1);

    // Swapped QK^T: mfma(K, Q) -> sacc[jt][r] = S[k = sigma(jt,4quad+r)][q = ln15]
    f32x4 sacc[4];
#pragma unroll
    for (int jt = 0; jt < 4; ++jt) sacc[jt] = (f32x4){0.f, 0.f, 0.f, 0.f};
#pragma unroll
    for (int ks = 0; ks < 4; ++ks) {
#pragma unroll
      for (int jt = 0; jt < 4; ++jt) {
        bf16x8 bk = *(const bf16x8*)&Ks[cur][(16 * jt + ln15) * 128
                                            + ((ks * 4 + quad) ^ swz) * 8];
        sacc[jt] = __builtin_amdgcn_mfma_f32_16x16x32_bf16(bk, aqr[ks], sacc[jt], 0, 0, 0);
      }
    }

    // mask (k local index = sigma-permuted) + scalar online softmax
    float sv[4][4];
#pragma unroll
    for (int jt = 0; jt < 4; ++jt) {
#pragma unroll
      for (int r = 0; r < 4; ++r) {
        int kl = ((jt & 2) << 4) + 8 * quad + ((jt & 1) << 2) + r;
        int jg = kt * 64 + kl;
        float x = sacc[jt][r] * scale;
        sv[jt][r] = (jg > ig) ? -10000.0f : x;
      }
    }

    float tmx = sv[0][0];
#pragma unroll
    for (int jt = 0; jt < 4; ++jt)
#pragma unroll
      for (int r = 0; r < 4; ++r) tmx = fmaxf(tmx, sv[jt][r]);
    tmx = fmaxf(tmx, __shfl_xor(tmx, 16));
    tmx = fmaxf(tmx, __shfl_xor(tmx, 32));

    float m_new = fmaxf(m_run, tmx);
    float alpha = __expf(m_run - m_new);
    m_run = m_new;

    float p[4][4];
    float ps = 0.0f;
#pragma unroll
    for (int jt = 0; jt < 4; ++jt)
#pragma unroll
      for (int r = 0; r < 4; ++r) {
        p[jt][r] = __expf(sv[jt][r] - m_run);
        ps += p[jt][r];
      }
    ps += __shfl_xor(ps, 16);
    ps += __shfl_xor(ps, 32);
    l_run = alpha * l_run + ps;

    // broadcast alpha to acc_o's row layout (q = 4*quad + r) and rescale O
    float aw[4];
#pragma unroll
    for (int r = 0; r < 4; ++r) aw[r] = __shfl(alpha, 4 * quad + r);
#pragma unroll
    for (int jt = 0; jt < 8; ++jt)
#pragma unroll
      for (int r = 0; r < 4; ++r) acc_o[jt][r] *= aw[r];

    // pack P -> PV A-fragments in-register (k = 8*quad+j for ap0, 32+8*quad+j for ap1)
    bf16x8 ap0, ap1;
#pragma unroll
    for (int j = 0; j < 4; ++j) {
      ap0[j]     = (short)f2bf(p[0][j]);
      ap0[4 + j] = (short)f2bf(p[1][j]);
      ap1[j]     = (short)f2bf(p[2][j]);
      ap1[4 + j] = (short)f2bf(p[3][j]);
    }

    __syncthreads();   // barrier#1: vmcnt drained -> V(kt) and K(kt+1) landed

    // PV: A = in-register P, V swizzled read from LDS
#pragma unroll
    for (int jt = 0; jt < 8; ++jt) {
      bf16x8 bv0 = *(const bf16x8*)&Vs[(16 * jt + ln15) * 64 + ((quad) ^ swz) * 8];
      acc_o[jt] = __builtin_amdgcn_mfma_f32_16x16x32_bf16(ap0, bv0, acc_o[jt], 0, 0, 0);
      bf16x8 bv1 = *(const bf16x8*)&Vs[(16 * jt + ln15) * 64 + ((4 + quad) ^ swz) * 8];
      acc_o[jt] = __builtin_amdgcn_mfma_f32_16x16x32_bf16(ap1, bv1, acc_o[jt], 0, 0, 0);
    }

    __syncthreads();   // barrier#2: Vs fully consumed -> next iter's V DMA may overwrite
    cur ^= 1;
  }
#undef STAGE_K
#undef STAGE_V

  // redistribute l_run (per-lane q=ln15) to output row layout (q = 4*quad + r)
  float rinv[4];
#pragma unroll
  for (int r = 0; r < 4; ++r) rinv[r] = 1.0f / __shfl(l_run, 4 * quad + r);
#pragma unroll
  for (int jt = 0; jt < 8; ++jt)
#pragma unroll
    for (int r = 0; r < 4; ++r) {
      int row = qb * 64 + 16 * w + 4 * quad + r;
      int col = 16 * jt + ln15;
      ctx[(size_t)row * CS + n * CH + col] = f2bf(acc_o[jt][r] * rinv[r]);
    }
}

// ---- launch ------------------------------------------------------------------------------
extern "C" void kernel_launch(void* const* d_in, const int* in_sizes, int n_in,
                              void* d_out, int out_size, void* d_ws, size_t ws_size,
                              hipStream_t stream) {
  const float* hidden  = (const float*)d_in[0];
  const float* w_qkv   = (const float*)d_in[2];
  const float* b_qkv   = (const float*)d_in[3];
  const float* w_dense = (const float*)d_in[4];
  float* out = (float*)d_out;

  char* ws = (char*)d_ws;

  const size_t wq_b    = (size_t)H3 * HID * 2;             // 25,165,824
  const size_t h_b     = (size_t)S_LEN * HID * 2;          //  8,388,608
  const size_t mixed_b = (size_t)S_LEN * H3 * 2;           // 25,165,824
  const size_t vt_b    = (size_t)NHEAD * HDIM * S_LEN * 2; //  8,388,608
  const size_t fast_need = wq_b + h_b + mixed_b + vt_b;    // 67,108,864 (64 MiB)

  if (ws_size >= fast_need) {
    // fast path: bf16 pre-convert + async-staged GEMMs
    ushort* WQ    = (ushort*)ws;                       // w_qkv bf16 (WD reuses this later)
    ushort* Hbf   = (ushort*)(ws + wq_b);
    ushort* mixed = (ushort*)(ws + wq_b + h_b);
    ushort* vt    = (ushort*)(ws + wq_b + h_b + mixed_b);
    ushort* WD    = WQ;                                // w_qkv dead after QKV GEMM
    ushort* ctx   = mixed;                             // q-slots of mixed (race-free)

    cvt_bf16<<<2048, 256, 0, stream>>>(hidden, Hbf, S_LEN * HID / 8);
    cvt_bf16<<<6144, 256, 0, stream>>>(w_qkv, WQ, H3 * HID / 8);
    gemm_async<128, 128, true, false><<<dim3(48, 16), 256, 0, stream>>>(
        Hbf, WQ, b_qkv, mixed, H3, HID, HID, 128);
    rope_kernel<<<8192, 256, 0, stream>>>(mixed);
    v_transpose<<<dim3(32, 16), 256, 0, stream>>>(mixed, vt);
    attn_kernel<<<dim3(32, 16), 256, 0, stream>>>(mixed, vt, ctx, H3, 384);
    cvt_bf16<<<2048, 256, 0, stream>>>(w_dense, WD, HID * HID / 8);
    gemm_async<64, 128, false, true><<<dim3(16, 32), 256, 0, stream>>>(
        ctx, WD, nullptr, out, HID, HID, H3, 384);
  } else {
    // fallback: round-4 proven path
    ushort* mixed = (ushort*)ws;
    ushort* vt    = (ushort*)(ws + mixed_b);
    const bool big = ws_size >= mixed_b + vt_b + (size_t)S_LEN * HID * 2;
    ushort* ctx = big ? (ushort*)(ws + mixed_b + vt_b) : mixed;
    const int CS = big ? HID  : H3;
    const int CH = big ? HDIM : 384;

    gemm_bt<true, true, false><<<dim3(48, 16), 256, 0, stream>>>(
        hidden, w_qkv, b_qkv, mixed, S_LEN, H3, HID, HID, HDIM);
    rope_kernel<<<8192, 256, 0, stream>>>(mixed);
    v_transpose<<<dim3(32, 16), 256, 0, stream>>>(mixed, vt);
    attn_kernel<<<dim3(32, 16), 256, 0, stream>>>(mixed, vt, ctx, CS, CH);
    gemm_bt<false, false, true><<<dim3(16, 16), 256, 0, stream>>>(
        ctx, w_dense, nullptr, out, S_LEN, HID, HID, CS, CH);
  }
}

// Round 10
// 284.540 us; speedup vs baseline: 1.5435x; 1.0564x over previous
//
#include <hip/hip_runtime.h>

// ParallelSelfAttention: S=2048 B=1 H=2048 NH=16 HD=128. I/O f32, internal bf16 MFMA.
// R14 = R13 + flash-decoding split-kt in attn. 512 blocks = 2/CU with same-qb pairs ->
// makespan 32 iters, ~51% util. Split qb>=16 into A=[0,half) / B=[half,qb] -> 768 pieces,
// 3/CU (LDS 49152*3 fits). Piece map exploits 256%48=16: CU triple {p,p+16,p+32} =
// {unsplit x, partA(31-x), partB(31-x)} = exactly 33 units, max piece 16 -> makespan ~16.
// Split pieces write f32 partials (O,m,l) into the dead WQ ws region; merge_kernel folds
// A+B into ctx. Per-iter math identical to verified R12/R13.

#define S_LEN 2048
#define NHEAD 16
#define HDIM  128
#define HID   2048
#define H3    6144

typedef short bf16x8 __attribute__((ext_vector_type(8)));
typedef float f32x4  __attribute__((ext_vector_type(4)));

__device__ __forceinline__ float bf2f(ushort u) {
  union { float f; unsigned int i; } v; v.i = ((unsigned int)u) << 16; return v.f;
}
__device__ __forceinline__ ushort f2bf(float f) {
  union { float f; unsigned int i; } v; v.f = f;
  unsigned int r = v.i + 0x7fffu + ((v.i >> 16) & 1u);
  return (ushort)(r >> 16);
}
__device__ __forceinline__ int4 cvt8(const float* p) {
  float4 a = *(const float4*)p, b = *(const float4*)(p + 4);
  union { ushort u[8]; int4 v; } r;
  r.u[0] = f2bf(a.x); r.u[1] = f2bf(a.y); r.u[2] = f2bf(a.z); r.u[3] = f2bf(a.w);
  r.u[4] = f2bf(b.x); r.u[5] = f2bf(b.y); r.u[6] = f2bf(b.z); r.u[7] = f2bf(b.w);
  return r.v;
}

// async global->LDS DMA, 16B per lane; LDS dest = wave-uniform base + lane*16
typedef __attribute__((address_space(1))) const unsigned int gu32;
typedef __attribute__((address_space(3))) unsigned int lu32;
__device__ __forceinline__ void async16(const void* g, void* l) {
  __builtin_amdgcn_global_load_lds((gu32*)g, (lu32*)l, 16, 0, 0);
}

// ---- f32 -> bf16 elementwise convert (8 elems/thread) -----------------------------------
__global__ __launch_bounds__(256) void cvt_bf16(const float* __restrict__ src,
                                                ushort* __restrict__ dst, int n8) {
  int i = blockIdx.x * 256 + threadIdx.x;
  if (i < n8) *(int4*)&dst[(size_t)i * 8] = cvt8(&src[(size_t)i * 8]);
}

// ---- Fast GEMM: C[M,N] = A @ W^T (+bias). A,W bf16; BK=64, swizzled DMA staging. --------
template<int BM, int BN, bool HAS_BIAS, bool OUT_F32>
__global__ __launch_bounds__(256) void gemm_async(const ushort* __restrict__ A,
                                                  const ushort* __restrict__ W,
                                                  const float* __restrict__ bias,
                                                  void* __restrict__ Cv,
                                                  int N, int K, int AS, int AH) {
  __shared__ __align__(16) ushort As[BM * 64];
  __shared__ __align__(16) ushort Ws[BN * 64];
  const int tid  = threadIdx.x;
  const int lane = tid & 63;
  const int w    = tid >> 6;
  const int wr   = w >> 1, wc = w & 1;
  const int quad = lane >> 4, ln15 = lane & 15;
  const int tm = blockIdx.y * BM, tn = blockIdx.x * BN;
  constexpr int MI = BM / 32, NJ = BN / 32;

  f32x4 acc[MI][NJ];
#pragma unroll
  for (int i = 0; i < MI; ++i)
#pragma unroll
    for (int j = 0; j < NJ; ++j) acc[i][j] = (f32x4){0.f, 0.f, 0.f, 0.f};

  const int lrow8 = lane >> 3;            // row within an 8-row issue block
  const int gsw   = (lane & 7) ^ lrow8;   // pre-swizzled global chunk for this lane
  const int sw    = ln15 & 7;             // read-side XOR key (row&7)

  for (int k0 = 0; k0 < K; k0 += 64) {
    for (int r = w; r < (BM + BN) / 8; r += 4) {
      if (r < BM / 8) {
        const int ka = k0 + gsw * 8;
        async16(&A[(size_t)(tm + r * 8 + lrow8) * AS + (ka >> 7) * AH + (ka & 127)],
                &As[r * 8 * 64]);
      } else {
        const int rb = r - BM / 8;
        async16(&W[(size_t)(tn + rb * 8 + lrow8) * K + k0 + gsw * 8],
                &Ws[rb * 8 * 64]);
      }
    }
    __syncthreads();
#pragma unroll
    for (int kk = 0; kk < 2; ++kk) {
      const int slot = ((kk * 4 + quad) ^ sw) * 8;
      bf16x8 af[MI], bw[NJ];
#pragma unroll
      for (int i = 0; i < MI; ++i)
        af[i] = *(const bf16x8*)&As[((BM / 2) * wr + 16 * i + ln15) * 64 + slot];
#pragma unroll
      for (int j = 0; j < NJ; ++j)
        bw[j] = *(const bf16x8*)&Ws[((BN / 2) * wc + 16 * j + ln15) * 64 + slot];
#pragma unroll
      for (int i = 0; i < MI; ++i)
#pragma unroll
        for (int j = 0; j < NJ; ++j)
          acc[i][j] = __builtin_amdgcn_mfma_f32_16x16x32_bf16(af[i], bw[j], acc[i][j], 0, 0, 0);
    }
    __syncthreads();
  }

#pragma unroll
  for (int i = 0; i < MI; ++i)
#pragma unroll
    for (int j = 0; j < NJ; ++j) {
      int col = tn + (BN / 2) * wc + 16 * j + ln15;
      float badd = HAS_BIAS ? bias[col] : 0.0f;
#pragma unroll
      for (int r = 0; r < 4; ++r) {
        int row = tm + (BM / 2) * wr + 16 * i + 4 * quad + r;
        float val = acc[i][j][r] + badd;
        if (OUT_F32) ((float*)Cv)[(size_t)row * N + col] = val;
        else         ((ushort*)Cv)[(size_t)row * N + col] = f2bf(val);
      }
    }
}

// ---- Fallback GEMM (round-4 proven): A f32-or-bf16, W f32, cvt in staging ---------------
template<bool A_F32, bool HAS_BIAS, bool OUT_F32>
__global__ __launch_bounds__(256) void gemm_bt(const void* __restrict__ Av,
                                               const float* __restrict__ W,
                                               const float* __restrict__ bias,
                                               void* __restrict__ Cv,
                                               int M, int N, int K, int AS, int AH) {
  __shared__ __align__(16) ushort As[128 * 40];
  __shared__ __align__(16) ushort Ws[128 * 40];
  const int tid  = threadIdx.x;
  const int lane = tid & 63;
  const int w    = tid >> 6;
  const int wr   = w >> 1, wc = w & 1;
  const int quad = lane >> 4, ln15 = lane & 15;
  const int tm = blockIdx.y * 128, tn = blockIdx.x * 128;

  f32x4 acc[4][4];
#pragma unroll
  for (int i = 0; i < 4; ++i)
#pragma unroll
    for (int j = 0; j < 4; ++j) acc[i][j] = (f32x4){0.f, 0.f, 0.f, 0.f};

  const int row0 = tid >> 2, row1 = row0 + 64;
  const int kp   = (tid & 3) * 8;

  for (int k0 = 0; k0 < K; k0 += 32) {
    const int ka   = k0 + kp;
    const int aoff = (ka >> 7) * AH + (ka & 127);
    if (A_F32) {
      const float* A = (const float*)Av;
      *(int4*)&As[row0 * 40 + kp] = cvt8(&A[(size_t)(tm + row0) * AS + aoff]);
      *(int4*)&As[row1 * 40 + kp] = cvt8(&A[(size_t)(tm + row1) * AS + aoff]);
    } else {
      const ushort* A = (const ushort*)Av;
      *(int4*)&As[row0 * 40 + kp] = *(const int4*)&A[(size_t)(tm + row0) * AS + aoff];
      *(int4*)&As[row1 * 40 + kp] = *(const int4*)&A[(size_t)(tm + row1) * AS + aoff];
    }
    *(int4*)&Ws[row0 * 40 + kp] = cvt8(&W[(size_t)(tn + row0) * K + ka]);
    *(int4*)&Ws[row1 * 40 + kp] = cvt8(&W[(size_t)(tn + row1) * K + ka]);
    __syncthreads();
    bf16x8 af[4], bw[4];
#pragma unroll
    for (int i = 0; i < 4; ++i)
      af[i] = *(const bf16x8*)&As[(64 * wr + 16 * i + ln15) * 40 + quad * 8];
#pragma unroll
    for (int j = 0; j < 4; ++j)
      bw[j] = *(const bf16x8*)&Ws[(64 * wc + 16 * j + ln15) * 40 + quad * 8];
#pragma unroll
    for (int i = 0; i < 4; ++i)
#pragma unroll
      for (int j = 0; j < 4; ++j)
        acc[i][j] = __builtin_amdgcn_mfma_f32_16x16x32_bf16(af[i], bw[j], acc[i][j], 0, 0, 0);
    __syncthreads();
  }

#pragma unroll
  for (int i = 0; i < 4; ++i)
#pragma unroll
    for (int j = 0; j < 4; ++j) {
      int col = tn + 64 * wc + 16 * j + ln15;
      float badd = HAS_BIAS ? bias[col] : 0.0f;
#pragma unroll
      for (int r = 0; r < 4; ++r) {
        int row = tm + 64 * wr + 16 * i + 4 * quad + r;
        float val = acc[i][j][r] + badd;
        if (OUT_F32) ((float*)Cv)[(size_t)row * N + col] = val;
        else         ((ushort*)Cv)[(size_t)row * N + col] = f2bf(val);
      }
    }
}

// ---- RoPE in place on q,k of mixed[s][n*384 + {q,k,v}] (bf16), float sincos -------------
__global__ __launch_bounds__(256) void rope_kernel(ushort* __restrict__ mixed) {
  int t = blockIdx.x * 256 + threadIdx.x;   // S*NH*64 threads
  int d = t & 63;
  int n = (t >> 6) & (NHEAD - 1);
  int s = t >> 10;
  ushort* base = mixed + (size_t)s * H3 + n * 384;
  float invf = exp2f((float)d * (-13.287712379549449f / 64.0f));
  float ang = (float)s * invf;
  float si, c; sincosf(ang, &si, &c);
  float q0 = bf2f(base[d]),       q1 = bf2f(base[64 + d]);
  float k0 = bf2f(base[128 + d]), k1 = bf2f(base[192 + d]);
  base[d]       = f2bf(q0 * c - q1 * si);
  base[64 + d]  = f2bf(q1 * c + q0 * si);
  base[128 + d] = f2bf(k0 * c - k1 * si);
  base[192 + d] = f2bf(k1 * c + k0 * si);
}

// ---- V transpose: mixed v-part (bf16) -> vt[n][d][s] ------------------------------------
__global__ __launch_bounds__(256) void v_transpose(const ushort* __restrict__ mixed,
                                                   ushort* __restrict__ vt) {
  __shared__ __align__(16) ushort Vl[64 * 136];
  const int tid = threadIdx.x;
  const int sb = blockIdx.x;
  const int n  = blockIdx.y;
#pragma unroll
  for (int it = 0; it < 4; ++it) {
    int c = tid + it * 256;
    int row = c >> 4, dp = (c & 15) * 8;
    *(int4*)&Vl[row * 136 + dp] =
        *(const int4*)&mixed[(size_t)(sb * 64 + row) * H3 + n * 384 + 256 + dp];
  }
  __syncthreads();
#pragma unroll
  for (int it = 0; it < 4; ++it) {
    int c = tid + it * 256;
    int d = c >> 3, sp = (c & 7) * 8;
    union { ushort u[8]; int4 v; } pk;
#pragma unroll
    for (int e = 0; e < 8; ++e) pk.u[e] = Vl[(sp + e) * 136 + d];
    *(int4*)&vt[((size_t)(n * 128 + d)) * S_LEN + sb * 64 + sp] = pk.v;
  }
}

// ---- Flash attention R14: split-kt pieces + R12 core (swapped QK^T, in-register P) ------
// part==nullptr: gridDim.x==32, piece p == qb full range (fallback path).
// part!=nullptr: gridDim.x==48 piece map (balanced triples mod 48):
//   p<16  -> unsplit qb=p            [0, qb+1)          -> ctx
//   p<32  -> partA  qb=47-p          [0, (qb+1)/2)      -> partial slot 2*(n*16+qb-16)
//   else  -> partB  qb=63-p          [(qb+1)/2, qb+1)   -> partial slot +1
// Partial layout (f32): O[64][128] + m[64] + l[64] = 8320 floats per slot.
__global__ __launch_bounds__(256, 3) void attn_kernel(const ushort* __restrict__ mixed,
                                                      const ushort* __restrict__ vt,
                                                      ushort* __restrict__ ctx,
                                                      int CS, int CH,
                                                      float* __restrict__ part) {
  __shared__ __align__(16) ushort Ks[2][64 * 128];  // DMA dest; rows PERMUTED by sigma
  __shared__ __align__(16) ushort Vs[128 * 64];     // DMA dest; chunk^=(row&7) via source

  const int tid  = threadIdx.x;
  const int lane = tid & 63;
  const int w    = tid >> 6;
  const int quad = lane >> 4, ln15 = lane & 15;
  const int p  = blockIdx.x;
  const int n  = blockIdx.y;
  const float scale = 0.08838834764831845f;

  int qb, kt0, kt1, pslot;
  if (part == nullptr) { qb = p;      kt0 = 0;             kt1 = qb + 1;        pslot = -1; }
  else if (p < 16)     { qb = p;      kt0 = 0;             kt1 = qb + 1;        pslot = -1; }
  else if (p < 32)     { qb = 47 - p; kt0 = 0;             kt1 = (qb + 1) >> 1; pslot = (n * 16 + qb - 16) * 2; }
  else                 { qb = 63 - p; kt0 = (qb + 1) >> 1; kt1 = qb + 1;        pslot = (n * 16 + qb - 16) * 2 + 1; }

  const ushort* Kg = mixed + n * 384 + 128;
  const ushort* Vg = vt + (size_t)n * 128 * S_LEN;

  // Q fragments (registers, whole kernel); lane holds Q row (16w+ln15), d = ks*32+quad*8..
  bf16x8 aqr[4];
#pragma unroll
  for (int ks = 0; ks < 4; ++ks)
    aqr[ks] = *(const bf16x8*)&mixed[(size_t)(qb * 64 + 16 * w + ln15) * H3 + n * 384
                                     + ks * 32 + quad * 8];

  f32x4 acc_o[8];
#pragma unroll
  for (int jt = 0; jt < 8; ++jt) acc_o[jt] = (f32x4){0.f, 0.f, 0.f, 0.f};
  float m_run = -1e30f, l_run = 0.0f;   // scalar: lane owns q = 16w + ln15

  // DMA geometry. K issue: 1KB = 4 rows x 16 chunks(16B). V issue: 1KB = 8 rows x 8 chunks.
  const int krow = lane >> 4, kcs = lane & 15;
  const int vrow = lane >> 3, vcs = lane & 7;
  const int swz  = ln15 & 7;   // read-side XOR key (LDS row & 7)

  // K row permutation sigma (see R12): lane's 16 P-values become its PV A-fragment.
#define STAGE_K(KT, BUF)                                                        \
  { _Pragma("unroll")                                                           \
    for (int i = 0; i < 4; ++i) {                                               \
      int sig = ((w & 2) << 4) + 8 * i + ((w & 1) << 2) + krow;                 \
      int kcl = kcs ^ ((i * 4 + krow) & 7);                                     \
      async16(&Kg[(size_t)((KT) * 64 + sig) * H3 + kcl * 8],                    \
              &Ks[BUF][(w * 16 + i * 4) * 128]);                                \
    } }
#define STAGE_V(KT)                                                             \
  { _Pragma("unroll")                                                           \
    for (int i = 0; i < 4; ++i) {                                               \
      int vr = w * 32 + i * 8 + vrow;                                           \
      int vcl = vcs ^ (vr & 7);                                                 \
      async16(&Vg[(size_t)vr * S_LEN + (KT) * 64 + vcl * 8],                    \
              &Vs[(w * 32 + i * 8) * 64]);                                      \
    } }

  int cur = 0;
  STAGE_K(kt0, 0);
  __syncthreads();   // drain: K(kt0) ready

  const int ig = qb * 64 + 16 * w + ln15;   // this lane's global q row

  for (int kt = kt0; kt < kt1; ++kt) {
    // Issue V(kt) and K(kt+1) DMAs; they land by barrier#1 (hidden under QK+softmax).
    STAGE_V(kt);
    if (kt + 1 < kt1) STAGE_K(kt + 1, cur ^ 1);

    // Swapped QK^T: mfma(K, Q) -> sacc[jt][r] = S[k = sigma(jt,4quad+r)][q = ln15]
    f32x4 sacc[4];
#pragma unroll
    for (int jt = 0; jt < 4; ++jt) sacc[jt] = (f32x4){0.f, 0.f, 0.f, 0.f};
#pragma unroll
    for (int ks = 0; ks < 4; ++ks) {
#pragma unroll
      for (int jt = 0; jt < 4; ++jt) {
        bf16x8 bk = *(const bf16x8*)&Ks[cur][(16 * jt + ln15) * 128
                                            + ((ks * 4 + quad) ^ swz) * 8];
        sacc[jt] = __builtin_amdgcn_mfma_f32_16x16x32_bf16(bk, aqr[ks], sacc[jt], 0, 0, 0);
      }
    }

    // mask (k local index = sigma-permuted) + scalar online softmax
    float sv[4][4];
#pragma unroll
    for (int jt = 0; jt < 4; ++jt) {
#pragma unroll
      for (int r = 0; r < 4; ++r) {
        int kl = ((jt & 2) << 4) + 8 * quad + ((jt & 1) << 2) + r;
        int jg = kt * 64 + kl;
        float x = sacc[jt][r] * scale;
        sv[jt][r] = (jg > ig) ? -10000.0f : x;
      }
    }

    float tmx = sv[0][0];
#pragma unroll
    for (int jt = 0; jt < 4; ++jt)
#pragma unroll
      for (int r = 0; r < 4; ++r) tmx = fmaxf(tmx, sv[jt][r]);
    tmx = fmaxf(tmx, __shfl_xor(tmx, 16));
    tmx = fmaxf(tmx, __shfl_xor(tmx, 32));

    float m_new = fmaxf(m_run, tmx);
    float alpha = __expf(m_run - m_new);
    m_run = m_new;

    float pv[4][4];
    float ps = 0.0f;
#pragma unroll
    for (int jt = 0; jt < 4; ++jt)
#pragma unroll
      for (int r = 0; r < 4; ++r) {
        pv[jt][r] = __expf(sv[jt][r] - m_run);
        ps += pv[jt][r];
      }
    ps += __shfl_xor(ps, 16);
    ps += __shfl_xor(ps, 32);
    l_run = alpha * l_run + ps;

    // broadcast alpha to acc_o's row layout (q = 4*quad + r) and rescale O
    float aw[4];
#pragma unroll
    for (int r = 0; r < 4; ++r) aw[r] = __shfl(alpha, 4 * quad + r);
#pragma unroll
    for (int jt = 0; jt < 8; ++jt)
#pragma unroll
      for (int r = 0; r < 4; ++r) acc_o[jt][r] *= aw[r];

    // pack P -> PV A-fragments in-register (k = 8*quad+j for ap0, 32+8*quad+j for ap1)
    bf16x8 ap0, ap1;
#pragma unroll
    for (int j = 0; j < 4; ++j) {
      ap0[j]     = (short)f2bf(pv[0][j]);
      ap0[4 + j] = (short)f2bf(pv[1][j]);
      ap1[j]     = (short)f2bf(pv[2][j]);
      ap1[4 + j] = (short)f2bf(pv[3][j]);
    }

    __syncthreads();   // barrier#1: vmcnt drained -> V(kt) and K(kt+1) landed

    // PV: A = in-register P, V swizzled read from LDS
#pragma unroll
    for (int jt = 0; jt < 8; ++jt) {
      bf16x8 bv0 = *(const bf16x8*)&Vs[(16 * jt + ln15) * 64 + ((quad) ^ swz) * 8];
      acc_o[jt] = __builtin_amdgcn_mfma_f32_16x16x32_bf16(ap0, bv0, acc_o[jt], 0, 0, 0);
      bf16x8 bv1 = *(const bf16x8*)&Vs[(16 * jt + ln15) * 64 + ((4 + quad) ^ swz) * 8];
      acc_o[jt] = __builtin_amdgcn_mfma_f32_16x16x32_bf16(ap1, bv1, acc_o[jt], 0, 0, 0);
    }

    __syncthreads();   // barrier#2: Vs fully consumed -> next iter's V DMA may overwrite
    cur ^= 1;
  }
#undef STAGE_K
#undef STAGE_V

  if (pslot < 0) {
    // final: normalize and write ctx. l_run redistribute (per-lane q=ln15) -> rows 4quad+r
    float rinv[4];
#pragma unroll
    for (int r = 0; r < 4; ++r) rinv[r] = 1.0f / __shfl(l_run, 4 * quad + r);
#pragma unroll
    for (int jt = 0; jt < 8; ++jt)
#pragma unroll
      for (int r = 0; r < 4; ++r) {
        int row = qb * 64 + 16 * w + 4 * quad + r;
        int col = 16 * jt + ln15;
        ctx[(size_t)row * CS + n * CH + col] = f2bf(acc_o[jt][r] * rinv[r]);
      }
  } else {
    // partial: write unnormalized O (f32) + m,l
    float* pp = part + (size_t)pslot * 8320;
#pragma unroll
    for (int jt = 0; jt < 8; ++jt)
#pragma unroll
      for (int r = 0; r < 4; ++r)
        pp[(16 * w + 4 * quad + r) * 128 + 16 * jt + ln15] = acc_o[jt][r];
    if (quad == 0) {
      pp[8192 + 16 * w + ln15] = m_run;
      pp[8256 + 16 * w + ln15] = l_run;
    }
  }
}

// ---- merge partials: ctx[qb*64+row] = (wA*OA + wB*OB) / (wA*lA + wB*lB) -----------------
__global__ __launch_bounds__(256) void merge_kernel(const float* __restrict__ part,
                                                    ushort* __restrict__ ctx,
                                                    int CS, int CH) {
  const int xqb = blockIdx.x, n = blockIdx.y;
  const int qb = 16 + xqb;
  const float* pA = part + (size_t)((n * 16 + xqb) * 2 + 0) * 8320;
  const float* pB = part + (size_t)((n * 16 + xqb) * 2 + 1) * 8320;
  const int row = threadIdx.x >> 2;
  const int c0  = (threadIdx.x & 3) * 32;
  float mA = pA[8192 + row], mB = pB[8192 + row];
  float lA = pA[8256 + row], lB = pB[8256 + row];
  float m  = fmaxf(mA, mB);
  float wA = __expf(mA - m), wB = __expf(mB - m);
  float rl = 1.0f / (wA * lA + wB * lB);
  wA *= rl; wB *= rl;
  ushort* dst = ctx + (size_t)(qb * 64 + row) * CS + n * CH + c0;
#pragma unroll
  for (int j = 0; j < 32; j += 4) {
    float4 a = *(const float4*)&pA[row * 128 + c0 + j];
    float4 b = *(const float4*)&pB[row * 128 + c0 + j];
    ushort4 o;
    o.x = f2bf(wA * a.x + wB * b.x);
    o.y = f2bf(wA * a.y + wB * b.y);
    o.z = f2bf(wA * a.z + wB * b.z);
    o.w = f2bf(wA * a.w + wB * b.w);
    *(ushort4*)&dst[j] = o;
  }
}

// ---- launch ------------------------------------------------------------------------------
extern "C" void kernel_launch(void* const* d_in, const int* in_sizes, int n_in,
                              void* d_out, int out_size, void* d_ws, size_t ws_size,
                              hipStream_t stream) {
  const float* hidden  = (const float*)d_in[0];
  const float* w_qkv   = (const float*)d_in[2];
  const float* b_qkv   = (const float*)d_in[3];
  const float* w_dense = (const float*)d_in[4];
  float* out = (float*)d_out;

  char* ws = (char*)d_ws;

  const size_t wq_b    = (size_t)H3 * HID * 2;             // 25,165,824
  const size_t h_b     = (size_t)S_LEN * HID * 2;          //  8,388,608
  const size_t mixed_b = (size_t)S_LEN * H3 * 2;           // 25,165,824
  const size_t vt_b    = (size_t)NHEAD * HDIM * S_LEN * 2; //  8,388,608
  const size_t fast_need = wq_b + h_b + mixed_b + vt_b;    // 67,108,864 (64 MiB)

  if (ws_size >= fast_need) {
    // fast path: bf16 pre-convert + async-staged GEMMs
    ushort* WQ    = (ushort*)ws;                       // w_qkv bf16 (WD reuses this later)
    ushort* Hbf   = (ushort*)(ws + wq_b);
    ushort* mixed = (ushort*)(ws + wq_b + h_b);
    ushort* vt    = (ushort*)(ws + wq_b + h_b + mixed_b);
    ushort* WD    = WQ;                                // w_qkv dead after QKV GEMM
    ushort* ctx   = mixed;                             // q-slots of mixed (race-free)
    float* partb  = (float*)ws;                        // WQ region: dead during attn;
                                                       // 512 slots * 33280B = 17MB < 24MB.
                                                       // Stream order: attn+merge finish
                                                       // before WD cvt overwrites.

    cvt_bf16<<<2048, 256, 0, stream>>>(hidden, Hbf, S_LEN * HID / 8);
    cvt_bf16<<<6144, 256, 0, stream>>>(w_qkv, WQ, H3 * HID / 8);
    gemm_async<128, 128, true, false><<<dim3(48, 16), 256, 0, stream>>>(
        Hbf, WQ, b_qkv, mixed, H3, HID, HID, 128);
    rope_kernel<<<8192, 256, 0, stream>>>(mixed);
    v_transpose<<<dim3(32, 16), 256, 0, stream>>>(mixed, vt);
    attn_kernel<<<dim3(48, 16), 256, 0, stream>>>(mixed, vt, ctx, H3, 384, partb);
    merge_kernel<<<dim3(16, 16), 256, 0, stream>>>(partb, ctx, H3, 384);
    cvt_bf16<<<2048, 256, 0, stream>>>(w_dense, WD, HID * HID / 8);
    gemm_async<64, 128, false, true><<<dim3(16, 32), 256, 0, stream>>>(
        ctx, WD, nullptr, out, HID, HID, H3, 384);
  } else {
    // fallback: round-4 proven path (unsplit attn, no partials)
    ushort* mixed = (ushort*)ws;
    ushort* vt    = (ushort*)(ws + mixed_b);
    const bool big = ws_size >= mixed_b + vt_b + (size_t)S_LEN * HID * 2;
    ushort* ctx = big ? (ushort*)(ws + mixed_b + vt_b) : mixed;
    const int CS = big ? HID  : H3;
    const int CH = big ? HDIM : 384;

    gemm_bt<true, true, false><<<dim3(48, 16), 256, 0, stream>>>(
        hidden, w_qkv, b_qkv, mixed, S_LEN, H3, HID, HID, HDIM);
    rope_kernel<<<8192, 256, 0, stream>>>(mixed);
    v_transpose<<<dim3(32, 16), 256, 0, stream>>>(mixed, vt);
    attn_kernel<<<dim3(32, 16), 256, 0, stream>>>(mixed, vt, ctx, CS, CH, nullptr);
    gemm_bt<false, false, true><<<dim3(16, 16), 256, 0, stream>>>(
        ctx, w_dense, nullptr, out, S_LEN, HID, HID, CS, CH);
  }
}